// Round 12
// baseline (746.635 us; speedup 1.0000x reference)
//
#include <hip/hip_runtime.h>
#include <math.h>

constexpr int N_ = 50000;
constexpr int E_ = 800000;
constexpr int IN_ = 64;
constexpr int HID_ = 128;
constexpr int G_ = 64;
constexpr float NEG_ = 0.2f;
constexpr float LOG2E_ = 1.44269504088896340736f;

#define ACT_NONE 0
#define ACT_RELU 1

typedef _Float16 half8 __attribute__((ext_vector_type(8)));
typedef _Float16 half2v __attribute__((ext_vector_type(2)));
typedef float floatx4 __attribute__((ext_vector_type(4)));

// ---------------- CSR build ----------------
__global__ __launch_bounds__(256) void hist_kernel(const int* __restrict__ dst,
                                                   int* __restrict__ deg, int e) {
  int i = blockIdx.x * 256 + threadIdx.x;
  if (i < e) atomicAdd(&deg[dst[i]], 1);
}

__global__ __launch_bounds__(256) void scan1_kernel(const int* __restrict__ deg,
                                                    int* __restrict__ excl,
                                                    int* __restrict__ bscan, int n) {
  __shared__ int sh[256];
  int t = threadIdx.x;
  int i = blockIdx.x * 256 + t;
  int v = (i < n) ? deg[i] : 0;
  sh[t] = v;
  __syncthreads();
  for (int off = 1; off < 256; off <<= 1) {
    int y = (t >= off) ? sh[t - off] : 0;
    __syncthreads();
    sh[t] += y;
    __syncthreads();
  }
  int incl = sh[t];
  if (i < n) excl[i] = incl - v;
  if (t == 255) bscan[blockIdx.x] = incl;
}

__global__ __launch_bounds__(256) void scan2_kernel(int* __restrict__ data, int nb) {
  __shared__ int sh[256];
  int t = threadIdx.x;
  int v = (t < nb) ? data[t] : 0;
  sh[t] = v;
  __syncthreads();
  for (int off = 1; off < 256; off <<= 1) {
    int y = (t >= off) ? sh[t - off] : 0;
    __syncthreads();
    sh[t] += y;
    __syncthreads();
  }
  if (t < nb) data[t] = sh[t] - v;  // exclusive
}

__global__ __launch_bounds__(256) void scan3_kernel(int* __restrict__ rowptr,
                                                    int* __restrict__ cursor,
                                                    const int* __restrict__ bscan,
                                                    int n, int e) {
  int i = blockIdx.x * 256 + threadIdx.x;
  if (i < n) {
    int v = rowptr[i] + bscan[blockIdx.x];
    rowptr[i] = v;
    cursor[i] = v;
  }
  if (i == n) rowptr[n] = e;
}

__global__ __launch_bounds__(256) void fill_kernel(const int* __restrict__ src,
                                                   const int* __restrict__ dst,
                                                   int* __restrict__ cursor,
                                                   int* __restrict__ csr, int e) {
  int i = blockIdx.x * 256 + threadIdx.x;
  if (i < e) {
    int d = dst[i];
    int p = atomicAdd(&cursor[d], 1);
    csr[p] = src[i];
  }
}

// ---------------- weight prep: transpose + fp16 hi/lo split (+ bias sum fused) ----------------
__global__ __launch_bounds__(256) void prep_w_kernel(
    const float* __restrict__ W_in, const float* __restrict__ W_res,
    const float* __restrict__ b_in, const float* __restrict__ b_res,
    const float* __restrict__ m0, const float* __restrict__ m1,
    const float* __restrict__ m2, const float* __restrict__ m3,
    const float* __restrict__ m4, const float* __restrict__ m5,
    const float* __restrict__ m6, const float* __restrict__ m7,
    const float* __restrict__ m8, const float* __restrict__ m9,
    _Float16* __restrict__ dst, float* __restrict__ bsum) {
  int idx = blockIdx.x * 256 + threadIdx.x;
  if (idx < 8192) {
    int n = idx >> 6, k = idx & 63;
    float v = W_in[k * 128 + n] + W_res[k * 128 + n];
    _Float16 h = (_Float16)v;
    dst[idx] = h;
    dst[8192 + idx] = (_Float16)(v - (float)h);
  } else if (idx < 8192 + 10 * 16384) {
    int r = idx - 8192;
    int j = r >> 14;
    int e = r & 16383;
    int n = e >> 7, k = e & 127;
    const float* S;
    switch (j) {
      case 0: S = m0; break; case 1: S = m1; break; case 2: S = m2; break;
      case 3: S = m3; break; case 4: S = m4; break; case 5: S = m5; break;
      case 6: S = m6; break; case 7: S = m7; break; case 8: S = m8; break;
      default: S = m9; break;
    }
    float v = S[k * 128 + n];
    _Float16 h = (_Float16)v;
    _Float16* base = dst + 16384 + j * 32768;
    base[e] = h;                       // e == n*128+k
    base[16384 + e] = (_Float16)(v - (float)h);
  } else if (idx < 8192 + 10 * 16384 + 128) {
    int k = idx - (8192 + 10 * 16384);
    bsum[k] = b_in[k] + b_res[k];
  }
}

// ---------------- fp16 hi/lo split of 8 floats (input-proj GEMM only) ----------------
__device__ inline void split8v(float4 a, float4 b, half8& h, half8& l) {
  float v0 = a.x, v1 = a.y, v2 = a.z, v3 = a.w;
  float v4 = b.x, v5 = b.y, v6 = b.z, v7 = b.w;
  _Float16 h0 = (_Float16)v0, h1 = (_Float16)v1, h2 = (_Float16)v2, h3 = (_Float16)v3;
  _Float16 h4 = (_Float16)v4, h5 = (_Float16)v5, h6 = (_Float16)v6, h7 = (_Float16)v7;
  h[0] = h0; h[1] = h1; h[2] = h2; h[3] = h3; h[4] = h4; h[5] = h5; h[6] = h6; h[7] = h7;
  l[0] = (_Float16)(v0 - (float)h0); l[1] = (_Float16)(v1 - (float)h1);
  l[2] = (_Float16)(v2 - (float)h2); l[3] = (_Float16)(v3 - (float)h3);
  l[4] = (_Float16)(v4 - (float)h4); l[5] = (_Float16)(v5 - (float)h5);
  l[6] = (_Float16)(v6 - (float)h6); l[7] = (_Float16)(v7 - (float)h7);
}

// ---- input-proj GEMM (fp32 A, hi/lo split): C16 = A[M,64]@W + bias ----
__global__ __launch_bounds__(256, 2) void gemm_rw_in(const float* __restrict__ A,
                                                     const _Float16* __restrict__ Wh,
                                                     const _Float16* __restrict__ Wl,
                                                     const float* __restrict__ bias,
                                                     _Float16* __restrict__ C, int M) {
  constexpr int K1 = 64, KK = 2;
  const int t = threadIdx.x;
  const int wave = t >> 6, lane = t & 63;
  const int quad = lane >> 4, l16 = lane & 15;
  const int nt0 = wave * 2;

  half8 wh[2][KK], wl[2][KK];
  float bb[2];
  int col[2];
#pragma unroll
  for (int i = 0; i < 2; ++i) {
    col[i] = (nt0 + i) * 16 + l16;
    bb[i] = bias[col[i]];
#pragma unroll
    for (int k = 0; k < KK; ++k) {
      size_t off = (size_t)col[i] * K1 + k * 32 + quad * 8;
      wh[i][k] = *reinterpret_cast<const half8*>(Wh + off);
      wl[i][k] = *reinterpret_cast<const half8*>(Wl + off);
    }
  }
  const int r0 = blockIdx.x * 64;
#pragma unroll
  for (int tt = 0; tt < 4; ++tt) {
    int tb = r0 + tt * 16;
    if (tb >= M) break;
    int arow = tb + l16;
    if (arow >= M) arow = M - 1;
    const float* ap = A + (size_t)arow * K1 + quad * 8;
    floatx4 acc[2];
    acc[0] = (floatx4){0.f, 0.f, 0.f, 0.f};
    acc[1] = (floatx4){0.f, 0.f, 0.f, 0.f};
#pragma unroll
    for (int k = 0; k < KK; ++k) {
      float4 a0 = *reinterpret_cast<const float4*>(ap + k * 32);
      float4 a1 = *reinterpret_cast<const float4*>(ap + k * 32 + 4);
      half8 ah, al;
      split8v(a0, a1, ah, al);
      acc[0] = __builtin_amdgcn_mfma_f32_16x16x32_f16(ah, wh[0][k], acc[0], 0, 0, 0);
      acc[0] = __builtin_amdgcn_mfma_f32_16x16x32_f16(ah, wl[0][k], acc[0], 0, 0, 0);
      acc[0] = __builtin_amdgcn_mfma_f32_16x16x32_f16(al, wh[0][k], acc[0], 0, 0, 0);
      acc[1] = __builtin_amdgcn_mfma_f32_16x16x32_f16(ah, wh[1][k], acc[1], 0, 0, 0);
      acc[1] = __builtin_amdgcn_mfma_f32_16x16x32_f16(ah, wl[1][k], acc[1], 0, 0, 0);
      acc[1] = __builtin_amdgcn_mfma_f32_16x16x32_f16(al, wh[1][k], acc[1], 0, 0, 0);
    }
#pragma unroll
    for (int i = 0; i < 2; ++i) {
#pragma unroll
      for (int reg = 0; reg < 4; ++reg) {
        int r = tb + quad * 4 + reg;
        if (r < M) C[(size_t)r * 128 + col[i]] = (_Float16)(acc[i][reg] + bb[i]);
      }
    }
  }
}

// ---- fp16-A GEMM: C = act(A16[M,128]@W + bias); no split, 2 MFMA/tile ----
template <int ACT, typename OutT>
__global__ __launch_bounds__(256, 2) void gemm_rw16(const _Float16* __restrict__ A,
                                                    const _Float16* __restrict__ Wh,
                                                    const _Float16* __restrict__ Wl,
                                                    const float* __restrict__ bias,
                                                    OutT* __restrict__ C, int M) {
  const int t = threadIdx.x;
  const int wave = t >> 6, lane = t & 63;
  const int quad = lane >> 4, l16 = lane & 15;
  const int nt0 = wave * 2;

  half8 wh[2][4], wl[2][4];
  float bb[2];
  int col[2];
#pragma unroll
  for (int i = 0; i < 2; ++i) {
    col[i] = (nt0 + i) * 16 + l16;
    bb[i] = bias[col[i]];
#pragma unroll
    for (int k = 0; k < 4; ++k) {
      size_t off = (size_t)col[i] * 128 + k * 32 + quad * 8;
      wh[i][k] = *reinterpret_cast<const half8*>(Wh + off);
      wl[i][k] = *reinterpret_cast<const half8*>(Wl + off);
    }
  }
  const int r0 = blockIdx.x * 64;
#pragma unroll
  for (int tt = 0; tt < 4; ++tt) {
    int tb = r0 + tt * 16;
    if (tb >= M) break;
    int arow = tb + l16;
    if (arow >= M) arow = M - 1;
    const _Float16* ap = A + (size_t)arow * 128 + quad * 8;
    half8 a[4];
#pragma unroll
    for (int k = 0; k < 4; ++k) a[k] = *reinterpret_cast<const half8*>(ap + k * 32);
    floatx4 acc[2];
    acc[0] = (floatx4){0.f, 0.f, 0.f, 0.f};
    acc[1] = (floatx4){0.f, 0.f, 0.f, 0.f};
#pragma unroll
    for (int k = 0; k < 4; ++k) {
      acc[0] = __builtin_amdgcn_mfma_f32_16x16x32_f16(a[k], wh[0][k], acc[0], 0, 0, 0);
      acc[0] = __builtin_amdgcn_mfma_f32_16x16x32_f16(a[k], wl[0][k], acc[0], 0, 0, 0);
      acc[1] = __builtin_amdgcn_mfma_f32_16x16x32_f16(a[k], wh[1][k], acc[1], 0, 0, 0);
      acc[1] = __builtin_amdgcn_mfma_f32_16x16x32_f16(a[k], wl[1][k], acc[1], 0, 0, 0);
    }
#pragma unroll
    for (int i = 0; i < 2; ++i) {
#pragma unroll
      for (int reg = 0; reg < 4; ++reg) {
        int r = tb + quad * 4 + reg;
        if (r < M) {
          float v = acc[i][reg] + bb[i];
          if (ACT == ACT_RELU) v = fmaxf(v, 0.f);
          C[(size_t)r * 128 + col[i]] = (OutT)v;
        }
      }
    }
  }
}

// ---- fp16-A dual-output GEMM (GAT): C0 = A@W0+b0, C1 = A@W1+b1 ----
__global__ __launch_bounds__(256, 2) void gemm_rw16_dual_gat(const _Float16* __restrict__ A,
                                                             const _Float16* __restrict__ W0h,
                                                             const _Float16* __restrict__ W0l,
                                                             const _Float16* __restrict__ W1h,
                                                             const _Float16* __restrict__ W1l,
                                                             const float* __restrict__ b0,
                                                             const float* __restrict__ b1,
                                                             _Float16* __restrict__ C0,
                                                             _Float16* __restrict__ C1, int M) {
  const int t = threadIdx.x;
  const int wave = t >> 6, lane = t & 63;
  const int quad = lane >> 4, l16 = lane & 15;
  const int nt0 = wave * 2;

  half8 w0h[2][4], w0l[2][4], w1h[2][4], w1l[2][4];
  float bb0[2], bb1[2];
  int col[2];
#pragma unroll
  for (int i = 0; i < 2; ++i) {
    col[i] = (nt0 + i) * 16 + l16;
    bb0[i] = b0[col[i]];
    bb1[i] = b1[col[i]];
#pragma unroll
    for (int k = 0; k < 4; ++k) {
      size_t off = (size_t)col[i] * 128 + k * 32 + quad * 8;
      w0h[i][k] = *reinterpret_cast<const half8*>(W0h + off);
      w0l[i][k] = *reinterpret_cast<const half8*>(W0l + off);
      w1h[i][k] = *reinterpret_cast<const half8*>(W1h + off);
      w1l[i][k] = *reinterpret_cast<const half8*>(W1l + off);
    }
  }
  const int r0 = blockIdx.x * 64;
#pragma unroll
  for (int tt = 0; tt < 4; ++tt) {
    int tb = r0 + tt * 16;
    if (tb >= M) break;
    int arow = tb + l16;
    if (arow >= M) arow = M - 1;
    const _Float16* ap = A + (size_t)arow * 128 + quad * 8;
    half8 a[4];
#pragma unroll
    for (int k = 0; k < 4; ++k) a[k] = *reinterpret_cast<const half8*>(ap + k * 32);
    floatx4 acc0[2], acc1[2];
    acc0[0] = (floatx4){0.f, 0.f, 0.f, 0.f};
    acc0[1] = (floatx4){0.f, 0.f, 0.f, 0.f};
    acc1[0] = (floatx4){0.f, 0.f, 0.f, 0.f};
    acc1[1] = (floatx4){0.f, 0.f, 0.f, 0.f};
#pragma unroll
    for (int k = 0; k < 4; ++k) {
#pragma unroll
      for (int i = 0; i < 2; ++i) {
        acc0[i] = __builtin_amdgcn_mfma_f32_16x16x32_f16(a[k], w0h[i][k], acc0[i], 0, 0, 0);
        acc0[i] = __builtin_amdgcn_mfma_f32_16x16x32_f16(a[k], w0l[i][k], acc0[i], 0, 0, 0);
        acc1[i] = __builtin_amdgcn_mfma_f32_16x16x32_f16(a[k], w1h[i][k], acc1[i], 0, 0, 0);
        acc1[i] = __builtin_amdgcn_mfma_f32_16x16x32_f16(a[k], w1l[i][k], acc1[i], 0, 0, 0);
      }
    }
#pragma unroll
    for (int i = 0; i < 2; ++i) {
#pragma unroll
      for (int reg = 0; reg < 4; ++reg) {
        int r = tb + quad * 4 + reg;
        if (r < M) {
          C0[(size_t)r * 128 + col[i]] = (_Float16)(acc0[i][reg] + bb0[i]);
          C1[(size_t)r * 128 + col[i]] = (_Float16)(acc1[i][reg] + bb1[i]);
        }
      }
    }
  }
}

// ---- fp16-A dual-A GEMM (SAGE) + fused L2norm + LN + leaky; fp16 out ----
__global__ __launch_bounds__(256, 2) void gemm_rw16_dual_sage(const _Float16* __restrict__ A1,
                                                              const _Float16* __restrict__ W1h,
                                                              const _Float16* __restrict__ W1l,
                                                              const _Float16* __restrict__ A2,
                                                              const _Float16* __restrict__ W2h,
                                                              const _Float16* __restrict__ W2l,
                                                              const float* __restrict__ bias,
                                                              const float* __restrict__ lng,
                                                              const float* __restrict__ lnb,
                                                              _Float16* __restrict__ C, int M) {
  const int t = threadIdx.x;
  const int wave = t >> 6, lane = t & 63;
  const int quad = lane >> 4, l16 = lane & 15;
  const int nt0 = wave * 2;

  half8 w1h[2][4], w1l[2][4], w2h[2][4], w2l[2][4];
  float bb[2], gg[2], lb[2];
  int col[2];
#pragma unroll
  for (int i = 0; i < 2; ++i) {
    col[i] = (nt0 + i) * 16 + l16;
    bb[i] = bias[col[i]];
    gg[i] = lng[col[i]];
    lb[i] = lnb[col[i]];
#pragma unroll
    for (int k = 0; k < 4; ++k) {
      size_t off = (size_t)col[i] * 128 + k * 32 + quad * 8;
      w1h[i][k] = *reinterpret_cast<const half8*>(W1h + off);
      w1l[i][k] = *reinterpret_cast<const half8*>(W1l + off);
      w2h[i][k] = *reinterpret_cast<const half8*>(W2h + off);
      w2l[i][k] = *reinterpret_cast<const half8*>(W2l + off);
    }
  }
  __shared__ float2 red[2][4][16];  // [tile parity][wave][row]
  const int r0 = blockIdx.x * 64;
#pragma unroll 1
  for (int tt = 0; tt < 4; ++tt) {
    int tb = r0 + tt * 16;
    if (tb >= M) break;
    int arow = tb + l16;
    if (arow >= M) arow = M - 1;
    const _Float16* ap1 = A1 + (size_t)arow * 128 + quad * 8;
    const _Float16* ap2 = A2 + (size_t)arow * 128 + quad * 8;
    half8 a[4], b[4];
#pragma unroll
    for (int k = 0; k < 4; ++k) {
      a[k] = *reinterpret_cast<const half8*>(ap1 + k * 32);
      b[k] = *reinterpret_cast<const half8*>(ap2 + k * 32);
    }
    floatx4 acc[2];
    acc[0] = (floatx4){0.f, 0.f, 0.f, 0.f};
    acc[1] = (floatx4){0.f, 0.f, 0.f, 0.f};
#pragma unroll
    for (int k = 0; k < 4; ++k) {
#pragma unroll
      for (int i = 0; i < 2; ++i) {
        acc[i] = __builtin_amdgcn_mfma_f32_16x16x32_f16(a[k], w1h[i][k], acc[i], 0, 0, 0);
        acc[i] = __builtin_amdgcn_mfma_f32_16x16x32_f16(a[k], w1l[i][k], acc[i], 0, 0, 0);
        acc[i] = __builtin_amdgcn_mfma_f32_16x16x32_f16(b[k], w2h[i][k], acc[i], 0, 0, 0);
        acc[i] = __builtin_amdgcn_mfma_f32_16x16x32_f16(b[k], w2l[i][k], acc[i], 0, 0, 0);
      }
    }
    float v0[4], v1[4], p1[4], p2[4];
#pragma unroll
    for (int reg = 0; reg < 4; ++reg) {
      v0[reg] = acc[0][reg] + bb[0];
      v1[reg] = acc[1][reg] + bb[1];
      p1[reg] = v0[reg] + v1[reg];
      p2[reg] = v0[reg] * v0[reg] + v1[reg] * v1[reg];
    }
#pragma unroll
    for (int off = 1; off < 16; off <<= 1) {
#pragma unroll
      for (int reg = 0; reg < 4; ++reg) {
        p1[reg] += __shfl_xor(p1[reg], off, 64);
        p2[reg] += __shfl_xor(p2[reg], off, 64);
      }
    }
    int par = tt & 1;
    if (l16 == 0) {
#pragma unroll
      for (int reg = 0; reg < 4; ++reg)
        red[par][wave][quad * 4 + reg] = make_float2(p1[reg], p2[reg]);
    }
    __syncthreads();
#pragma unroll
    for (int reg = 0; reg < 4; ++reg) {
      int rr = quad * 4 + reg;
      float2 q0 = red[par][0][rr], q1 = red[par][1][rr];
      float2 q2 = red[par][2][rr], q3 = red[par][3][rr];
      float s1 = q0.x + q1.x + q2.x + q3.x;
      float s2 = q0.y + q1.y + q2.y + q3.y;
      float inv = 1.f / fmaxf(sqrtf(s2), 1e-12f);
      float mu = s1 * inv * (1.f / 128.f);
      float ex2 = (s2 * inv) * inv * (1.f / 128.f);
      float rstd = rsqrtf(ex2 - mu * mu + 1e-5f);
      int r = tb + rr;
      if (r < M) {
        float o0 = (v0[reg] * inv - mu) * rstd * gg[0] + lb[0];
        float o1 = (v1[reg] * inv - mu) * rstd * gg[1] + lb[1];
        o0 = fmaxf(o0, NEG_ * o0);
        o1 = fmaxf(o1, NEG_ * o1);
        C[(size_t)r * 128 + col[0]] = (_Float16)o0;
        C[(size_t)r * 128 + col[1]] = (_Float16)o1;
      }
    }
  }
}

// ---------------- GATv2 + LN + ELU; TWO nodes per wave (independent gather streams) ----------------
__global__ __launch_bounds__(256) void gat_ln_kernel(const _Float16* __restrict__ xl,
                                                     const _Float16* __restrict__ xr,
                                                     const float* __restrict__ att,
                                                     const float* __restrict__ gbias,
                                                     const int* __restrict__ rowptr,
                                                     const int* __restrict__ csr,
                                                     const float* __restrict__ lng,
                                                     const float* __restrict__ lnb,
                                                     _Float16* __restrict__ out, int n) {
  int wq = (blockIdx.x * 256 + threadIdx.x) >> 6;
  int lane = threadIdx.x & 63;
  int wA = 2 * wq;
  if (wA >= n) return;
  int wB = wA + 1;
  bool hasB = wB < n;
  const int h = lane >> 3, e = lane & 7;
  const char* __restrict__ xbase = (const char*)(xl + h * 16);

  half2v at2[8];
  {
    const float2* ap = reinterpret_cast<const float2*>(att + h * 16);
#pragma unroll
    for (int i = 0; i < 8; ++i) {
      float2 a = ap[i];
      at2[i][0] = (_Float16)(a.x * LOG2E_);
      at2[i][1] = (_Float16)(a.y * LOG2E_);
    }
  }
  const half2v negc = {(_Float16)NEG_, (_Float16)NEG_};

  half2v xrA[8], xrB[8];
  {
    const uint4* xp = reinterpret_cast<const uint4*>(xr + (size_t)wA * 128 + h * 16);
    uint4 u0 = xp[0], u1 = xp[1];
    unsigned uu[8] = {u0.x, u0.y, u0.z, u0.w, u1.x, u1.y, u1.z, u1.w};
#pragma unroll
    for (int i = 0; i < 8; ++i) xrA[i] = __builtin_bit_cast(half2v, uu[i]);
    int wb = hasB ? wB : wA;
    const uint4* xq = reinterpret_cast<const uint4*>(xr + (size_t)wb * 128 + h * 16);
    uint4 v0 = xq[0], v1 = xq[1];
    unsigned vv[8] = {v0.x, v0.y, v0.z, v0.w, v1.x, v1.y, v1.z, v1.w};
#pragma unroll
    for (int i = 0; i < 8; ++i) xrB[i] = __builtin_bit_cast(half2v, vv[i]);
  }

  float m0A, denA, accA[16];
  float m0B = 0.f, denB = 0.f, accB[16];
#pragma unroll
  for (int i = 0; i < 16; ++i) accB[i] = 0.f;
  {  // self loop A
    const uint4* sp = reinterpret_cast<const uint4*>(xbase + (size_t)wA * 256);
    uint4 u0 = sp[0], u1 = sp[1];
    unsigned uu[8] = {u0.x, u0.y, u0.z, u0.w, u1.x, u1.y, u1.z, u1.w};
    float p = 0.f;
#pragma unroll
    for (int i = 0; i < 8; ++i) {
      half2v x = __builtin_bit_cast(half2v, uu[i]);
      half2v z = x + xrA[i];
      half2v zl = __builtin_elementwise_max(z, z * negc);
      p = __builtin_amdgcn_fdot2(zl, at2[i], p, false);
    }
    m0A = p;
    float w = (e == 0) ? 1.f : 0.f;
    denA = w;
#pragma unroll
    for (int i = 0; i < 8; ++i) {
      half2v x = __builtin_bit_cast(half2v, uu[i]);
      accA[2 * i] = w * (float)x[0];
      accA[2 * i + 1] = w * (float)x[1];
    }
  }
  if (hasB) {  // self loop B
    const uint4* sp = reinterpret_cast<const uint4*>(xbase + (size_t)wB * 256);
    uint4 u0 = sp[0], u1 = sp[1];
    unsigned uu[8] = {u0.x, u0.y, u0.z, u0.w, u1.x, u1.y, u1.z, u1.w};
    float p = 0.f;
#pragma unroll
    for (int i = 0; i < 8; ++i) {
      half2v x = __builtin_bit_cast(half2v, uu[i]);
      half2v z = x + xrB[i];
      half2v zl = __builtin_elementwise_max(z, z * negc);
      p = __builtin_amdgcn_fdot2(zl, at2[i], p, false);
    }
    m0B = p;
    float w = (e == 0) ? 1.f : 0.f;
    denB = w;
#pragma unroll
    for (int i = 0; i < 8; ++i) {
      half2v x = __builtin_bit_cast(half2v, uu[i]);
      accB[2 * i] = w * (float)x[0];
      accB[2 * i + 1] = w * (float)x[1];
    }
  }

  int baseA = rowptr[wA], endA = rowptr[wA + 1];
  int baseB = 0, endB = 0;
  if (hasB) { baseB = endA; endB = rowptr[wB + 1]; }  // rows adjacent in CSR

  while (baseA < endA || baseB < endB) {
    bool doA = baseA < endA, doB = baseB < endB;
    uint4 au0, au1, bu0, bu1;
    bool vA = false, vB = false;
    if (doA) {
      int idx = baseA + e;
      vA = idx < endA;
      int ci = vA ? idx : endA - 1;
      int s = csr[ci];
      const uint4* gp = reinterpret_cast<const uint4*>(xbase + (size_t)s * 256);
      au0 = gp[0];
      au1 = gp[1];
    }
    if (doB) {
      int idx = baseB + e;
      vB = idx < endB;
      int ci = vB ? idx : endB - 1;
      int s = csr[ci];
      const uint4* gp = reinterpret_cast<const uint4*>(xbase + (size_t)s * 256);
      bu0 = gp[0];
      bu1 = gp[1];
    }
    if (doA) {
      unsigned uu[8] = {au0.x, au0.y, au0.z, au0.w, au1.x, au1.y, au1.z, au1.w};
      float p = 0.f;
#pragma unroll
      for (int i = 0; i < 8; ++i) {
        half2v x = __builtin_bit_cast(half2v, uu[i]);
        half2v z = x + xrA[i];
        half2v zl = __builtin_elementwise_max(z, z * negc);
        p = __builtin_amdgcn_fdot2(zl, at2[i], p, false);
      }
      float w = vA ? exp2f(p - m0A) : 0.f;
      denA += w;
#pragma unroll
      for (int i = 0; i < 8; ++i) {
        half2v x = __builtin_bit_cast(half2v, uu[i]);
        accA[2 * i] += w * (float)x[0];
        accA[2 * i + 1] += w * (float)x[1];
      }
      baseA += 8;
    }
    if (doB) {
      unsigned uu[8] = {bu0.x, bu0.y, bu0.z, bu0.w, bu1.x, bu1.y, bu1.z, bu1.w};
      float p = 0.f;
#pragma unroll
      for (int i = 0; i < 8; ++i) {
        half2v x = __builtin_bit_cast(half2v, uu[i]);
        half2v z = x + xrB[i];
        half2v zl = __builtin_elementwise_max(z, z * negc);
        p = __builtin_amdgcn_fdot2(zl, at2[i], p, false);
      }
      float w = vB ? exp2f(p - m0B) : 0.f;
      denB += w;
#pragma unroll
      for (int i = 0; i < 8; ++i) {
        half2v x = __builtin_bit_cast(half2v, uu[i]);
        accB[2 * i] += w * (float)x[0];
        accB[2 * i + 1] += w * (float)x[1];
      }
      baseB += 8;
    }
  }

  // epilogue helper: reduce across 8 e-slots, LN + ELU, fp16 store
  int c = h * 16 + 2 * e;
  float2 bv = reinterpret_cast<const float2*>(gbias + c)[0];
  float2 gvv = reinterpret_cast<const float2*>(lng + c)[0];
  float2 lbv = reinterpret_cast<const float2*>(lnb + c)[0];
#pragma unroll
  for (int nodesel = 0; nodesel < 2; ++nodesel) {
    if (nodesel == 1 && !hasB) break;
    float den = nodesel ? denB : denA;
    float* acc = nodesel ? accB : accA;
    int wid = nodesel ? wB : wA;
#pragma unroll
    for (int off = 1; off < 8; off <<= 1) {
      den += __shfl_xor(den, off, 64);
#pragma unroll
      for (int i = 0; i < 16; ++i) acc[i] += __shfl_xor(acc[i], off, 64);
    }
    float inv = 1.f / (den + 1e-16f);
    float o0 = acc[2 * e] * inv + bv.x;
    float o1 = acc[2 * e + 1] * inv + bv.y;
    float s1 = o0 + o1;
    float s2 = o0 * o0 + o1 * o1;
#pragma unroll
    for (int off = 1; off < 64; off <<= 1) {
      s1 += __shfl_xor(s1, off, 64);
      s2 += __shfl_xor(s2, off, 64);
    }
    float mu = s1 * (1.f / 128.f);
    float var = s2 * (1.f / 128.f) - mu * mu;
    float rstd = rsqrtf(var + 1e-5f);
    float e0 = (o0 - mu) * rstd * gvv.x + lbv.x;
    float e1 = (o1 - mu) * rstd * gvv.y + lbv.y;
    e0 = e0 > 0.f ? e0 : exp2f(e0 * LOG2E_) - 1.f;
    e1 = e1 > 0.f ? e1 : exp2f(e1 * LOG2E_) - 1.f;
    half2v o;
    o[0] = (_Float16)e0;
    o[1] = (_Float16)e1;
    reinterpret_cast<half2v*>(out)[wid * 64 + (c >> 1)] = o;
  }
}

// ---------------- SAGE mean aggregation; TWO nodes per wave ----------------
__global__ __launch_bounds__(256) void sage_agg_kernel(const _Float16* __restrict__ xp,
                                                       const int* __restrict__ rowptr,
                                                       const int* __restrict__ csr,
                                                       _Float16* __restrict__ mean, int n) {
  int wq = (blockIdx.x * 256 + threadIdx.x) >> 6;
  int lane = threadIdx.x & 63;
  int wA = 2 * wq;
  if (wA >= n) return;
  int wB = wA + 1;
  bool hasB = wB < n;
  const int g = lane >> 3, e = lane & 7;
  const char* __restrict__ xbase = (const char*)(xp + g * 16);

  float accA[16], accB[16];
#pragma unroll
  for (int i = 0; i < 16; ++i) { accA[i] = 0.f; accB[i] = 0.f; }

  int baseA = rowptr[wA], endA = rowptr[wA + 1];
  int begA = baseA;
  int baseB = 0, endB = 0, begB = 0;
  if (hasB) { baseB = endA; begB = baseB; endB = rowptr[wB + 1]; }

  while (baseA < endA || baseB < endB) {
    bool doA = baseA < endA, doB = baseB < endB;
    uint4 au0, au1, bu0, bu1;
    bool vA = false, vB = false;
    if (doA) {
      int idx = baseA + e;
      vA = idx < endA;
      int ci = vA ? idx : endA - 1;
      int s = csr[ci];
      const uint4* gp = reinterpret_cast<const uint4*>(xbase + (size_t)s * 256);
      au0 = gp[0];
      au1 = gp[1];
    }
    if (doB) {
      int idx = baseB + e;
      vB = idx < endB;
      int ci = vB ? idx : endB - 1;
      int s = csr[ci];
      const uint4* gp = reinterpret_cast<const uint4*>(xbase + (size_t)s * 256);
      bu0 = gp[0];
      bu1 = gp[1];
    }
    if (doA) {
      unsigned uu[8] = {au0.x, au0.y, au0.z, au0.w, au1.x, au1.y, au1.z, au1.w};
      float w = vA ? 1.f : 0.f;
#pragma unroll
      for (int i = 0; i < 8; ++i) {
        half2v x = __builtin_bit_cast(half2v, uu[i]);
        accA[2 * i] += w * (float)x[0];
        accA[2 * i + 1] += w * (float)x[1];
      }
      baseA += 8;
    }
    if (doB) {
      unsigned uu[8] = {bu0.x, bu0.y, bu0.z, bu0.w, bu1.x, bu1.y, bu1.z, bu1.w};
      float w = vB ? 1.f : 0.f;
#pragma unroll
      for (int i = 0; i < 8; ++i) {
        half2v x = __builtin_bit_cast(half2v, uu[i]);
        accB[2 * i] += w * (float)x[0];
        accB[2 * i + 1] += w * (float)x[1];
      }
      baseB += 8;
    }
  }

  int c = g * 16 + 2 * e;
#pragma unroll
  for (int nodesel = 0; nodesel < 2; ++nodesel) {
    if (nodesel == 1 && !hasB) break;
    float* acc = nodesel ? accB : accA;
    int wid = nodesel ? wB : wA;
    int deg = nodesel ? (endB - begB) : (endA - begA);
#pragma unroll
    for (int off = 1; off < 8; off <<= 1) {
#pragma unroll
      for (int i = 0; i < 16; ++i) acc[i] += __shfl_xor(acc[i], off, 64);
    }
    float inv = 1.f / fmaxf((float)deg, 1.f);
    half2v o;
    o[0] = (_Float16)(acc[2 * e] * inv);
    o[1] = (_Float16)(acc[2 * e + 1] * inv);
    reinterpret_cast<half2v*>(mean)[wid * 64 + (c >> 1)] = o;
  }
}

// ---------------- JK max + sigmoid gate + mean-pool (fp16 inputs) ----------------
__global__ __launch_bounds__(256) void jk_pool_kernel(const _Float16* __restrict__ x0,
                                                      const _Float16* __restrict__ x1,
                                                      const _Float16* __restrict__ x2,
                                                      const _Float16* __restrict__ x3,
                                                      const float* __restrict__ wap,
                                                      const float* __restrict__ bap,
                                                      const int* __restrict__ batch,
                                                      float* __restrict__ pooled,
                                                      float* __restrict__ cnt, int n,
                                                      int chunk) {
  int wid = (blockIdx.x * 256 + threadIdx.x) >> 6;
  int lane = threadIdx.x & 63;
  int start = wid * chunk;
  if (start >= n) return;
  int end = start + chunk;
  if (end > n) end = n;

  const float2 wv = reinterpret_cast<const float2*>(wap)[lane];
  const float b0 = bap[0];

  int cur = -1;
  float2 acc = make_float2(0.f, 0.f);
  float c = 0.f;

  for (int i = start; i < end; ++i) {
    int off = i * 64 + lane;
    half2v a0 = reinterpret_cast<const half2v*>(x0)[off];
    half2v a1 = reinterpret_cast<const half2v*>(x1)[off];
    half2v a2 = reinterpret_cast<const half2v*>(x2)[off];
    half2v a3 = reinterpret_cast<const half2v*>(x3)[off];
    half2v m01 = __builtin_elementwise_max(a0, a1);
    half2v m23 = __builtin_elementwise_max(a2, a3);
    half2v mm = __builtin_elementwise_max(m01, m23);
    float2 v = make_float2((float)mm[0], (float)mm[1]);
    float p = v.x * wv.x + v.y * wv.y;
#pragma unroll
    for (int o = 1; o < 64; o <<= 1) p += __shfl_xor(p, o, 64);
    float a = 1.f / (1.f + exp2f(-(p + b0) * LOG2E_));
    int bg = batch[i];
    if (bg != cur) {
      if (cur >= 0) {
        atomicAdd(&pooled[cur * 128 + 2 * lane], acc.x);
        atomicAdd(&pooled[cur * 128 + 2 * lane + 1], acc.y);
        if (lane == 0) atomicAdd(&cnt[cur], c);
      }
      cur = bg;
      acc = make_float2(0.f, 0.f);
      c = 0.f;
    }
    acc.x += v.x * a;
    acc.y += v.y * a;
    c += 1.f;
  }
  if (cur >= 0) {
    atomicAdd(&pooled[cur * 128 + 2 * lane], acc.x);
    atomicAdd(&pooled[cur * 128 + 2 * lane + 1], acc.y);
    if (lane == 0) atomicAdd(&cnt[cur], c);
  }
}

// ---------------- final MLP: one block per graph ----------------
__global__ __launch_bounds__(128) void mlp_kernel(const float* __restrict__ pooled,
                                                  const float* __restrict__ cnt,
                                                  const float* __restrict__ Wc1,
                                                  const float* __restrict__ bc1,
                                                  const float* __restrict__ a1,
                                                  const float* __restrict__ Wc2,
                                                  const float* __restrict__ bc2,
                                                  const float* __restrict__ a2,
                                                  const float* __restrict__ Wc3,
                                                  const float* __restrict__ bc3,
                                                  float* __restrict__ out) {
  __shared__ float sh[128];
  __shared__ float sh2[128];
  __shared__ float sh3[64];
  int g = blockIdx.x, t = threadIdx.x;
  float inv = 1.f / fmaxf(cnt[g], 1.f);
  sh[t] = pooled[g * 128 + t] * inv;
  __syncthreads();
  float z = bc1[t];
  for (int k = 0; k < 128; ++k) z += sh[k] * Wc1[k * 128 + t];
  float al = a1[0];
  z = z >= 0.f ? z : al * z;
  sh2[t] = z;
  __syncthreads();
  if (t < 64) {
    float z2 = bc2[t];
    for (int k = 0; k < 128; ++k) z2 += sh2[k] * Wc2[k * 64 + t];
    float a2v = a2[0];
    z2 = z2 >= 0.f ? z2 : a2v * z2;
    sh3[t] = z2;
  }
  __syncthreads();
  if (t < 2) {
    float o = bc3[t];
    for (int k = 0; k < 64; ++k) o += sh3[k] * Wc3[k * 2 + t];
    out[g * 2 + t] = o;
  }
}

// ================= host =================
extern "C" void kernel_launch(void* const* d_in, const int* in_sizes, int n_in,
                              void* d_out, int out_size, void* d_ws, size_t ws_size,
                              hipStream_t stream) {
  const float* x = (const float*)d_in[0];
  const int* ei = (const int*)d_in[1];
  const int* batch = (const int*)d_in[2];
  const float* W_in = (const float*)d_in[3];
  const float* b_in = (const float*)d_in[4];
  const float* W_res = (const float*)d_in[5];
  const float* b_res = (const float*)d_in[6];
  const float* g0_Wl = (const float*)d_in[7];
  const float* g0_bl = (const float*)d_in[8];
  const float* g0_Wr = (const float*)d_in[9];
  const float* g0_br = (const float*)d_in[10];
  const float* g0_att = (const float*)d_in[11];
  const float* g0_bias = (const float*)d_in[12];
  const float* g2_Wl = (const float*)d_in[13];
  const float* g2_bl = (const float*)d_in[14];
  const float* g2_Wr = (const float*)d_in[15];
  const float* g2_br = (const float*)d_in[16];
  const float* g2_att = (const float*)d_in[17];
  const float* g2_bias = (const float*)d_in[18];
  const float* s1_Wp = (const float*)d_in[19];
  const float* s1_bp = (const float*)d_in[20];
  const float* s1_Wl = (const float*)d_in[21];
  const float* s1_bl = (const float*)d_in[22];
  const float* s1_Wr = (const float*)d_in[23];
  const float* s3_Wp = (const float*)d_in[24];
  const float* s3_bp = (const float*)d_in[25];
  const float* s3_Wl = (const float*)d_in[26];
  const float* s3_bl = (const float*)d_in[27];
  const float* s3_Wr = (const float*)d_in[28];
  const float* ln_g = (const float*)d_in[29];
  const float* ln_b = (const float*)d_in[30];
  const float* Wap = (const float*)d_in[31];
  const float* bap = (const float*)d_in[32];
  const float* Wc1 = (const float*)d_in[33];
  const float* bc1 = (const float*)d_in[34];
  const float* a1 = (const float*)d_in[35];
  const float* Wc2 = (const float*)d_in[36];
  const float* bc2 = (const float*)d_in[37];
  const float* a2 = (const float*)d_in[38];
  const float* Wc3 = (const float*)d_in[39];
  const float* bc3 = (const float*)d_in[40];
  float* out = (float*)d_out;

  char* w = (char*)d_ws;
  auto alloc = [&](size_t bytes) -> void* {
    void* p = (void*)w;
    w += (bytes + 255) & ~(size_t)255;
    return p;
  };
  int* deg_cursor = (int*)alloc((size_t)N_ * 4);
  int* rowptr = (int*)alloc((size_t)(N_ + 1) * 4);
  int* bscan = (int*)alloc(256 * 4);
  int* csr = (int*)alloc((size_t)E_ * 4);
  float* bsumf = (float*)alloc((size_t)HID_ * 4);
  float* pooled = (float*)alloc((size_t)G_ * HID_ * 4);
  float* cntf = (float*)alloc((size_t)G_ * 4);
  _Float16* wsp = (_Float16*)alloc((size_t)(16384 + 10 * 32768) * 2);
  size_t bigh = (size_t)N_ * HID_ * 2;
  _Float16* T1 = (_Float16*)alloc(bigh);
  _Float16* T2 = (_Float16*)alloc(bigh);
  _Float16* H0 = (_Float16*)alloc(bigh);
  _Float16* H1 = (_Float16*)alloc(bigh);
  _Float16* B0 = (_Float16*)alloc(bigh);
  _Float16* B1 = (_Float16*)alloc(bigh);
  _Float16* B2 = (_Float16*)alloc(bigh);
  _Float16* B3 = (_Float16*)alloc(bigh);

  const _Float16* WsT_h = wsp;
  const _Float16* WsT_l = wsp + 8192;
  auto WTh = [&](int j) { return (const _Float16*)(wsp + 16384 + j * 32768); };
  auto WTl = [&](int j) { return (const _Float16*)(wsp + 16384 + j * 32768 + 16384); };
  // j: 0 g0_Wl, 1 g0_Wr, 2 s1_Wp, 3 s1_Wl, 4 s1_Wr, 5 g2_Wl, 6 g2_Wr, 7 s3_Wp, 8 s3_Wl, 9 s3_Wr

  const int EB = (E_ + 255) / 256;
  const int NB256 = (N_ + 255) / 256;
  const int WB2 = ((N_ + 1) / 2 + 3) / 4;  // 2 nodes per wave
  const int GB = (N_ + 63) / 64;

  // ---- CSR build ----
  hipMemsetAsync(deg_cursor, 0, (size_t)N_ * 4, stream);
  hist_kernel<<<EB, 256, 0, stream>>>(ei + E_, deg_cursor, E_);
  scan1_kernel<<<NB256, 256, 0, stream>>>(deg_cursor, rowptr, bscan, N_);
  scan2_kernel<<<1, 256, 0, stream>>>(bscan, NB256);
  scan3_kernel<<<NB256, 256, 0, stream>>>(rowptr, deg_cursor, bscan, N_, E_);
  fill_kernel<<<EB, 256, 0, stream>>>(ei, ei + E_, deg_cursor, csr, E_);

  // ---- weight prep (incl. bias sum) ----
  prep_w_kernel<<<(8192 + 10 * 16384 + 128 + 255) / 256, 256, 0, stream>>>(
      W_in, W_res, b_in, b_res, g0_Wl, g0_Wr, s1_Wp, s1_Wl, s1_Wr, g2_Wl, g2_Wr, s3_Wp,
      s3_Wl, s3_Wr, wsp, bsumf);

  // ---- input proj ----
  gemm_rw_in<<<GB, 256, 0, stream>>>(x, WsT_h, WsT_l, bsumf, T2, N_);

  // ---- GAT layer 0 ----
  gemm_rw16_dual_gat<<<GB, 256, 0, stream>>>(T2, WTh(0), WTl(0), WTh(1), WTl(1), g0_bl,
                                             g0_br, H0, H1, N_);
  gat_ln_kernel<<<WB2, 256, 0, stream>>>(H0, H1, g0_att, g0_bias, rowptr, csr,
                                         ln_g + 0 * 128, ln_b + 0 * 128, B0, N_);

  // ---- SAGE layer 1 ----
  gemm_rw16<ACT_RELU, _Float16><<<GB, 256, 0, stream>>>(B0, WTh(2), WTl(2), s1_bp, H0, N_);
  sage_agg_kernel<<<WB2, 256, 0, stream>>>(H0, rowptr, csr, T1, N_);
  gemm_rw16_dual_sage<<<GB, 256, 0, stream>>>(T1, WTh(3), WTl(3), B0, WTh(4), WTl(4), s1_bl,
                                              ln_g + 1 * 128, ln_b + 1 * 128, B1, N_);

  // ---- GAT layer 2 ----
  gemm_rw16_dual_gat<<<GB, 256, 0, stream>>>(B1, WTh(5), WTl(5), WTh(6), WTl(6), g2_bl,
                                             g2_br, H0, H1, N_);
  gat_ln_kernel<<<WB2, 256, 0, stream>>>(H0, H1, g2_att, g2_bias, rowptr, csr,
                                         ln_g + 2 * 128, ln_b + 2 * 128, B2, N_);

  // ---- SAGE layer 3 ----
  gemm_rw16<ACT_RELU, _Float16><<<GB, 256, 0, stream>>>(B2, WTh(7), WTl(7), s3_bp, H0, N_);
  sage_agg_kernel<<<WB2, 256, 0, stream>>>(H0, rowptr, csr, T1, N_);
  gemm_rw16_dual_sage<<<GB, 256, 0, stream>>>(T1, WTh(8), WTl(8), B2, WTh(9), WTl(9), s3_bl,
                                              ln_g + 3 * 128, ln_b + 3 * 128, B3, N_);

  // ---- JK max + gate + pool + MLP ----
  hipMemsetAsync(pooled, 0, (size_t)G_ * HID_ * 4 + (size_t)G_ * 4, stream);
  {
    const int chunk = 12;
    int nwaves = (N_ + chunk - 1) / chunk;
    int nblocks = (nwaves + 3) / 4;
    jk_pool_kernel<<<nblocks, 256, 0, stream>>>(B0, B1, B2, B3, Wap, bap, batch,
                                                pooled, cntf, N_, chunk);
  }
  mlp_kernel<<<G_, 128, 0, stream>>>(pooled, cntf, Wc1, bc1, a1, Wc2, bc2, a2, Wc3, bc3, out);
}

// Round 13
// 637.480 us; speedup vs baseline: 1.1712x; 1.1712x over previous
//
#include <hip/hip_runtime.h>
#include <math.h>

constexpr int N_ = 50000;
constexpr int E_ = 800000;
constexpr int IN_ = 64;
constexpr int HID_ = 128;
constexpr int G_ = 64;
constexpr float NEG_ = 0.2f;
constexpr float LOG2E_ = 1.44269504088896340736f;

#define ACT_NONE 0
#define ACT_RELU 1

typedef _Float16 half8 __attribute__((ext_vector_type(8)));
typedef _Float16 half2v __attribute__((ext_vector_type(2)));
typedef float floatx4 __attribute__((ext_vector_type(4)));

// ---------------- CSR build ----------------
__global__ __launch_bounds__(256) void hist_kernel(const int* __restrict__ dst,
                                                   int* __restrict__ deg, int e) {
  int i = blockIdx.x * 256 + threadIdx.x;
  if (i < e) atomicAdd(&deg[dst[i]], 1);
}

__global__ __launch_bounds__(256) void scan1_kernel(const int* __restrict__ deg,
                                                    int* __restrict__ excl,
                                                    int* __restrict__ bscan, int n) {
  __shared__ int sh[256];
  int t = threadIdx.x;
  int i = blockIdx.x * 256 + t;
  int v = (i < n) ? deg[i] : 0;
  sh[t] = v;
  __syncthreads();
  for (int off = 1; off < 256; off <<= 1) {
    int y = (t >= off) ? sh[t - off] : 0;
    __syncthreads();
    sh[t] += y;
    __syncthreads();
  }
  int incl = sh[t];
  if (i < n) excl[i] = incl - v;
  if (t == 255) bscan[blockIdx.x] = incl;
}

__global__ __launch_bounds__(256) void scan2_kernel(int* __restrict__ data, int nb) {
  __shared__ int sh[256];
  int t = threadIdx.x;
  int v = (t < nb) ? data[t] : 0;
  sh[t] = v;
  __syncthreads();
  for (int off = 1; off < 256; off <<= 1) {
    int y = (t >= off) ? sh[t - off] : 0;
    __syncthreads();
    sh[t] += y;
    __syncthreads();
  }
  if (t < nb) data[t] = sh[t] - v;  // exclusive
}

__global__ __launch_bounds__(256) void scan3_kernel(int* __restrict__ rowptr,
                                                    int* __restrict__ cursor,
                                                    const int* __restrict__ bscan,
                                                    int n, int e) {
  int i = blockIdx.x * 256 + threadIdx.x;
  if (i < n) {
    int v = rowptr[i] + bscan[blockIdx.x];
    rowptr[i] = v;
    cursor[i] = v;
  }
  if (i == n) rowptr[n] = e;
}

__global__ __launch_bounds__(256) void fill_kernel(const int* __restrict__ src,
                                                   const int* __restrict__ dst,
                                                   int* __restrict__ cursor,
                                                   int* __restrict__ csr, int e) {
  int i = blockIdx.x * 256 + threadIdx.x;
  if (i < e) {
    int d = dst[i];
    int p = atomicAdd(&cursor[d], 1);
    csr[p] = src[i];
  }
}

// ---------------- weight prep: transpose + fp16 hi/lo split (+ bias sum fused) ----------------
__global__ __launch_bounds__(256) void prep_w_kernel(
    const float* __restrict__ W_in, const float* __restrict__ W_res,
    const float* __restrict__ b_in, const float* __restrict__ b_res,
    const float* __restrict__ m0, const float* __restrict__ m1,
    const float* __restrict__ m2, const float* __restrict__ m3,
    const float* __restrict__ m4, const float* __restrict__ m5,
    const float* __restrict__ m6, const float* __restrict__ m7,
    const float* __restrict__ m8, const float* __restrict__ m9,
    _Float16* __restrict__ dst, float* __restrict__ bsum) {
  int idx = blockIdx.x * 256 + threadIdx.x;
  if (idx < 8192) {
    int n = idx >> 6, k = idx & 63;
    float v = W_in[k * 128 + n] + W_res[k * 128 + n];
    _Float16 h = (_Float16)v;
    dst[idx] = h;
    dst[8192 + idx] = (_Float16)(v - (float)h);
  } else if (idx < 8192 + 10 * 16384) {
    int r = idx - 8192;
    int j = r >> 14;
    int e = r & 16383;
    int n = e >> 7, k = e & 127;
    const float* S;
    switch (j) {
      case 0: S = m0; break; case 1: S = m1; break; case 2: S = m2; break;
      case 3: S = m3; break; case 4: S = m4; break; case 5: S = m5; break;
      case 6: S = m6; break; case 7: S = m7; break; case 8: S = m8; break;
      default: S = m9; break;
    }
    float v = S[k * 128 + n];
    _Float16 h = (_Float16)v;
    _Float16* base = dst + 16384 + j * 32768;
    base[e] = h;                       // e == n*128+k
    base[16384 + e] = (_Float16)(v - (float)h);
  } else if (idx < 8192 + 10 * 16384 + 128) {
    int k = idx - (8192 + 10 * 16384);
    bsum[k] = b_in[k] + b_res[k];
  }
}

// ---------------- fp16 hi/lo split of 8 floats (input-proj GEMM only) ----------------
__device__ inline void split8v(float4 a, float4 b, half8& h, half8& l) {
  float v0 = a.x, v1 = a.y, v2 = a.z, v3 = a.w;
  float v4 = b.x, v5 = b.y, v6 = b.z, v7 = b.w;
  _Float16 h0 = (_Float16)v0, h1 = (_Float16)v1, h2 = (_Float16)v2, h3 = (_Float16)v3;
  _Float16 h4 = (_Float16)v4, h5 = (_Float16)v5, h6 = (_Float16)v6, h7 = (_Float16)v7;
  h[0] = h0; h[1] = h1; h[2] = h2; h[3] = h3; h[4] = h4; h[5] = h5; h[6] = h6; h[7] = h7;
  l[0] = (_Float16)(v0 - (float)h0); l[1] = (_Float16)(v1 - (float)h1);
  l[2] = (_Float16)(v2 - (float)h2); l[3] = (_Float16)(v3 - (float)h3);
  l[4] = (_Float16)(v4 - (float)h4); l[5] = (_Float16)(v5 - (float)h5);
  l[6] = (_Float16)(v6 - (float)h6); l[7] = (_Float16)(v7 - (float)h7);
}

// ---- input-proj GEMM (fp32 A, hi/lo split): C16 = A[M,64]@W + bias ----
__global__ __launch_bounds__(256, 2) void gemm_rw_in(const float* __restrict__ A,
                                                     const _Float16* __restrict__ Wh,
                                                     const _Float16* __restrict__ Wl,
                                                     const float* __restrict__ bias,
                                                     _Float16* __restrict__ C, int M) {
  constexpr int K1 = 64, KK = 2;
  const int t = threadIdx.x;
  const int wave = t >> 6, lane = t & 63;
  const int quad = lane >> 4, l16 = lane & 15;
  const int nt0 = wave * 2;

  half8 wh[2][KK], wl[2][KK];
  float bb[2];
  int col[2];
#pragma unroll
  for (int i = 0; i < 2; ++i) {
    col[i] = (nt0 + i) * 16 + l16;
    bb[i] = bias[col[i]];
#pragma unroll
    for (int k = 0; k < KK; ++k) {
      size_t off = (size_t)col[i] * K1 + k * 32 + quad * 8;
      wh[i][k] = *reinterpret_cast<const half8*>(Wh + off);
      wl[i][k] = *reinterpret_cast<const half8*>(Wl + off);
    }
  }
  const int r0 = blockIdx.x * 64;
#pragma unroll
  for (int tt = 0; tt < 4; ++tt) {
    int tb = r0 + tt * 16;
    if (tb >= M) break;
    int arow = tb + l16;
    if (arow >= M) arow = M - 1;
    const float* ap = A + (size_t)arow * K1 + quad * 8;
    floatx4 acc[2];
    acc[0] = (floatx4){0.f, 0.f, 0.f, 0.f};
    acc[1] = (floatx4){0.f, 0.f, 0.f, 0.f};
#pragma unroll
    for (int k = 0; k < KK; ++k) {
      float4 a0 = *reinterpret_cast<const float4*>(ap + k * 32);
      float4 a1 = *reinterpret_cast<const float4*>(ap + k * 32 + 4);
      half8 ah, al;
      split8v(a0, a1, ah, al);
      acc[0] = __builtin_amdgcn_mfma_f32_16x16x32_f16(ah, wh[0][k], acc[0], 0, 0, 0);
      acc[0] = __builtin_amdgcn_mfma_f32_16x16x32_f16(ah, wl[0][k], acc[0], 0, 0, 0);
      acc[0] = __builtin_amdgcn_mfma_f32_16x16x32_f16(al, wh[0][k], acc[0], 0, 0, 0);
      acc[1] = __builtin_amdgcn_mfma_f32_16x16x32_f16(ah, wh[1][k], acc[1], 0, 0, 0);
      acc[1] = __builtin_amdgcn_mfma_f32_16x16x32_f16(ah, wl[1][k], acc[1], 0, 0, 0);
      acc[1] = __builtin_amdgcn_mfma_f32_16x16x32_f16(al, wh[1][k], acc[1], 0, 0, 0);
    }
#pragma unroll
    for (int i = 0; i < 2; ++i) {
#pragma unroll
      for (int reg = 0; reg < 4; ++reg) {
        int r = tb + quad * 4 + reg;
        if (r < M) C[(size_t)r * 128 + col[i]] = (_Float16)(acc[i][reg] + bb[i]);
      }
    }
  }
}

// ---- fp16-A GEMM: C = act(A16[M,128]@W + bias); no split, 2 MFMA/tile ----
template <int ACT, typename OutT>
__global__ __launch_bounds__(256, 2) void gemm_rw16(const _Float16* __restrict__ A,
                                                    const _Float16* __restrict__ Wh,
                                                    const _Float16* __restrict__ Wl,
                                                    const float* __restrict__ bias,
                                                    OutT* __restrict__ C, int M) {
  const int t = threadIdx.x;
  const int wave = t >> 6, lane = t & 63;
  const int quad = lane >> 4, l16 = lane & 15;
  const int nt0 = wave * 2;

  half8 wh[2][4], wl[2][4];
  float bb[2];
  int col[2];
#pragma unroll
  for (int i = 0; i < 2; ++i) {
    col[i] = (nt0 + i) * 16 + l16;
    bb[i] = bias[col[i]];
#pragma unroll
    for (int k = 0; k < 4; ++k) {
      size_t off = (size_t)col[i] * 128 + k * 32 + quad * 8;
      wh[i][k] = *reinterpret_cast<const half8*>(Wh + off);
      wl[i][k] = *reinterpret_cast<const half8*>(Wl + off);
    }
  }
  const int r0 = blockIdx.x * 64;
#pragma unroll
  for (int tt = 0; tt < 4; ++tt) {
    int tb = r0 + tt * 16;
    if (tb >= M) break;
    int arow = tb + l16;
    if (arow >= M) arow = M - 1;
    const _Float16* ap = A + (size_t)arow * 128 + quad * 8;
    half8 a[4];
#pragma unroll
    for (int k = 0; k < 4; ++k) a[k] = *reinterpret_cast<const half8*>(ap + k * 32);
    floatx4 acc[2];
    acc[0] = (floatx4){0.f, 0.f, 0.f, 0.f};
    acc[1] = (floatx4){0.f, 0.f, 0.f, 0.f};
#pragma unroll
    for (int k = 0; k < 4; ++k) {
      acc[0] = __builtin_amdgcn_mfma_f32_16x16x32_f16(a[k], wh[0][k], acc[0], 0, 0, 0);
      acc[0] = __builtin_amdgcn_mfma_f32_16x16x32_f16(a[k], wl[0][k], acc[0], 0, 0, 0);
      acc[1] = __builtin_amdgcn_mfma_f32_16x16x32_f16(a[k], wh[1][k], acc[1], 0, 0, 0);
      acc[1] = __builtin_amdgcn_mfma_f32_16x16x32_f16(a[k], wl[1][k], acc[1], 0, 0, 0);
    }
#pragma unroll
    for (int i = 0; i < 2; ++i) {
#pragma unroll
      for (int reg = 0; reg < 4; ++reg) {
        int r = tb + quad * 4 + reg;
        if (r < M) {
          float v = acc[i][reg] + bb[i];
          if (ACT == ACT_RELU) v = fmaxf(v, 0.f);
          C[(size_t)r * 128 + col[i]] = (OutT)v;
        }
      }
    }
  }
}

// ---- fp16-A dual-output GEMM (GAT): C0 = A@W0+b0, C1 = A@W1+b1 ----
__global__ __launch_bounds__(256, 2) void gemm_rw16_dual_gat(const _Float16* __restrict__ A,
                                                             const _Float16* __restrict__ W0h,
                                                             const _Float16* __restrict__ W0l,
                                                             const _Float16* __restrict__ W1h,
                                                             const _Float16* __restrict__ W1l,
                                                             const float* __restrict__ b0,
                                                             const float* __restrict__ b1,
                                                             _Float16* __restrict__ C0,
                                                             _Float16* __restrict__ C1, int M) {
  const int t = threadIdx.x;
  const int wave = t >> 6, lane = t & 63;
  const int quad = lane >> 4, l16 = lane & 15;
  const int nt0 = wave * 2;

  half8 w0h[2][4], w0l[2][4], w1h[2][4], w1l[2][4];
  float bb0[2], bb1[2];
  int col[2];
#pragma unroll
  for (int i = 0; i < 2; ++i) {
    col[i] = (nt0 + i) * 16 + l16;
    bb0[i] = b0[col[i]];
    bb1[i] = b1[col[i]];
#pragma unroll
    for (int k = 0; k < 4; ++k) {
      size_t off = (size_t)col[i] * 128 + k * 32 + quad * 8;
      w0h[i][k] = *reinterpret_cast<const half8*>(W0h + off);
      w0l[i][k] = *reinterpret_cast<const half8*>(W0l + off);
      w1h[i][k] = *reinterpret_cast<const half8*>(W1h + off);
      w1l[i][k] = *reinterpret_cast<const half8*>(W1l + off);
    }
  }
  const int r0 = blockIdx.x * 64;
#pragma unroll
  for (int tt = 0; tt < 4; ++tt) {
    int tb = r0 + tt * 16;
    if (tb >= M) break;
    int arow = tb + l16;
    if (arow >= M) arow = M - 1;
    const _Float16* ap = A + (size_t)arow * 128 + quad * 8;
    half8 a[4];
#pragma unroll
    for (int k = 0; k < 4; ++k) a[k] = *reinterpret_cast<const half8*>(ap + k * 32);
    floatx4 acc0[2], acc1[2];
    acc0[0] = (floatx4){0.f, 0.f, 0.f, 0.f};
    acc0[1] = (floatx4){0.f, 0.f, 0.f, 0.f};
    acc1[0] = (floatx4){0.f, 0.f, 0.f, 0.f};
    acc1[1] = (floatx4){0.f, 0.f, 0.f, 0.f};
#pragma unroll
    for (int k = 0; k < 4; ++k) {
#pragma unroll
      for (int i = 0; i < 2; ++i) {
        acc0[i] = __builtin_amdgcn_mfma_f32_16x16x32_f16(a[k], w0h[i][k], acc0[i], 0, 0, 0);
        acc0[i] = __builtin_amdgcn_mfma_f32_16x16x32_f16(a[k], w0l[i][k], acc0[i], 0, 0, 0);
        acc1[i] = __builtin_amdgcn_mfma_f32_16x16x32_f16(a[k], w1h[i][k], acc1[i], 0, 0, 0);
        acc1[i] = __builtin_amdgcn_mfma_f32_16x16x32_f16(a[k], w1l[i][k], acc1[i], 0, 0, 0);
      }
    }
#pragma unroll
    for (int i = 0; i < 2; ++i) {
#pragma unroll
      for (int reg = 0; reg < 4; ++reg) {
        int r = tb + quad * 4 + reg;
        if (r < M) {
          C0[(size_t)r * 128 + col[i]] = (_Float16)(acc0[i][reg] + bb0[i]);
          C1[(size_t)r * 128 + col[i]] = (_Float16)(acc1[i][reg] + bb1[i]);
        }
      }
    }
  }
}

// ---- fp16-A dual-A GEMM (SAGE) + fused L2norm + LN + leaky; fp16 out ----
__global__ __launch_bounds__(256, 2) void gemm_rw16_dual_sage(const _Float16* __restrict__ A1,
                                                              const _Float16* __restrict__ W1h,
                                                              const _Float16* __restrict__ W1l,
                                                              const _Float16* __restrict__ A2,
                                                              const _Float16* __restrict__ W2h,
                                                              const _Float16* __restrict__ W2l,
                                                              const float* __restrict__ bias,
                                                              const float* __restrict__ lng,
                                                              const float* __restrict__ lnb,
                                                              _Float16* __restrict__ C, int M) {
  const int t = threadIdx.x;
  const int wave = t >> 6, lane = t & 63;
  const int quad = lane >> 4, l16 = lane & 15;
  const int nt0 = wave * 2;

  half8 w1h[2][4], w1l[2][4], w2h[2][4], w2l[2][4];
  float bb[2], gg[2], lb[2];
  int col[2];
#pragma unroll
  for (int i = 0; i < 2; ++i) {
    col[i] = (nt0 + i) * 16 + l16;
    bb[i] = bias[col[i]];
    gg[i] = lng[col[i]];
    lb[i] = lnb[col[i]];
#pragma unroll
    for (int k = 0; k < 4; ++k) {
      size_t off = (size_t)col[i] * 128 + k * 32 + quad * 8;
      w1h[i][k] = *reinterpret_cast<const half8*>(W1h + off);
      w1l[i][k] = *reinterpret_cast<const half8*>(W1l + off);
      w2h[i][k] = *reinterpret_cast<const half8*>(W2h + off);
      w2l[i][k] = *reinterpret_cast<const half8*>(W2l + off);
    }
  }
  __shared__ float2 red[2][4][16];  // [tile parity][wave][row]
  const int r0 = blockIdx.x * 64;
#pragma unroll 1
  for (int tt = 0; tt < 4; ++tt) {
    int tb = r0 + tt * 16;
    if (tb >= M) break;
    int arow = tb + l16;
    if (arow >= M) arow = M - 1;
    const _Float16* ap1 = A1 + (size_t)arow * 128 + quad * 8;
    const _Float16* ap2 = A2 + (size_t)arow * 128 + quad * 8;
    half8 a[4], b[4];
#pragma unroll
    for (int k = 0; k < 4; ++k) {
      a[k] = *reinterpret_cast<const half8*>(ap1 + k * 32);
      b[k] = *reinterpret_cast<const half8*>(ap2 + k * 32);
    }
    floatx4 acc[2];
    acc[0] = (floatx4){0.f, 0.f, 0.f, 0.f};
    acc[1] = (floatx4){0.f, 0.f, 0.f, 0.f};
#pragma unroll
    for (int k = 0; k < 4; ++k) {
#pragma unroll
      for (int i = 0; i < 2; ++i) {
        acc[i] = __builtin_amdgcn_mfma_f32_16x16x32_f16(a[k], w1h[i][k], acc[i], 0, 0, 0);
        acc[i] = __builtin_amdgcn_mfma_f32_16x16x32_f16(a[k], w1l[i][k], acc[i], 0, 0, 0);
        acc[i] = __builtin_amdgcn_mfma_f32_16x16x32_f16(b[k], w2h[i][k], acc[i], 0, 0, 0);
        acc[i] = __builtin_amdgcn_mfma_f32_16x16x32_f16(b[k], w2l[i][k], acc[i], 0, 0, 0);
      }
    }
    float v0[4], v1[4], p1[4], p2[4];
#pragma unroll
    for (int reg = 0; reg < 4; ++reg) {
      v0[reg] = acc[0][reg] + bb[0];
      v1[reg] = acc[1][reg] + bb[1];
      p1[reg] = v0[reg] + v1[reg];
      p2[reg] = v0[reg] * v0[reg] + v1[reg] * v1[reg];
    }
#pragma unroll
    for (int off = 1; off < 16; off <<= 1) {
#pragma unroll
      for (int reg = 0; reg < 4; ++reg) {
        p1[reg] += __shfl_xor(p1[reg], off, 64);
        p2[reg] += __shfl_xor(p2[reg], off, 64);
      }
    }
    int par = tt & 1;
    if (l16 == 0) {
#pragma unroll
      for (int reg = 0; reg < 4; ++reg)
        red[par][wave][quad * 4 + reg] = make_float2(p1[reg], p2[reg]);
    }
    __syncthreads();
#pragma unroll
    for (int reg = 0; reg < 4; ++reg) {
      int rr = quad * 4 + reg;
      float2 q0 = red[par][0][rr], q1 = red[par][1][rr];
      float2 q2 = red[par][2][rr], q3 = red[par][3][rr];
      float s1 = q0.x + q1.x + q2.x + q3.x;
      float s2 = q0.y + q1.y + q2.y + q3.y;
      float inv = 1.f / fmaxf(sqrtf(s2), 1e-12f);
      float mu = s1 * inv * (1.f / 128.f);
      float ex2 = (s2 * inv) * inv * (1.f / 128.f);
      float rstd = rsqrtf(ex2 - mu * mu + 1e-5f);
      int r = tb + rr;
      if (r < M) {
        float o0 = (v0[reg] * inv - mu) * rstd * gg[0] + lb[0];
        float o1 = (v1[reg] * inv - mu) * rstd * gg[1] + lb[1];
        o0 = fmaxf(o0, NEG_ * o0);
        o1 = fmaxf(o1, NEG_ * o1);
        C[(size_t)r * 128 + col[0]] = (_Float16)o0;
        C[(size_t)r * 128 + col[1]] = (_Float16)o1;
      }
    }
  }
}

// ---------------- GATv2 + LN + ELU; lane=(head, edge-slot); fp16 in/out (R11 body) ----------------
__global__ __launch_bounds__(256) void gat_ln_kernel(const _Float16* __restrict__ xl,
                                                     const _Float16* __restrict__ xr,
                                                     const float* __restrict__ att,
                                                     const float* __restrict__ gbias,
                                                     const int* __restrict__ rowptr,
                                                     const int* __restrict__ csr,
                                                     const float* __restrict__ lng,
                                                     const float* __restrict__ lnb,
                                                     _Float16* __restrict__ out, int n) {
  int wid = (blockIdx.x * 256 + threadIdx.x) >> 6;
  int lane = threadIdx.x & 63;
  if (wid >= n) return;
  const int h = lane >> 3, e = lane & 7;
  const char* __restrict__ xbase = (const char*)(xl + h * 16);

  half2v xr2[8], at2[8];
  {
    const uint4* xrp = reinterpret_cast<const uint4*>(xr + (size_t)wid * 128 + h * 16);
    uint4 u0 = xrp[0], u1 = xrp[1];
    unsigned uu[8] = {u0.x, u0.y, u0.z, u0.w, u1.x, u1.y, u1.z, u1.w};
#pragma unroll
    for (int i = 0; i < 8; ++i) xr2[i] = __builtin_bit_cast(half2v, uu[i]);
    const float2* ap = reinterpret_cast<const float2*>(att + h * 16);
#pragma unroll
    for (int i = 0; i < 8; ++i) {
      float2 a = ap[i];
      at2[i][0] = (_Float16)(a.x * LOG2E_);
      at2[i][1] = (_Float16)(a.y * LOG2E_);
    }
  }
  const half2v negc = {(_Float16)NEG_, (_Float16)NEG_};

  float m0, den;
  float acc[16];
  {
    const uint4* sp = reinterpret_cast<const uint4*>(xbase + (size_t)wid * 256);
    uint4 u0 = sp[0], u1 = sp[1];
    unsigned uu[8] = {u0.x, u0.y, u0.z, u0.w, u1.x, u1.y, u1.z, u1.w};
    float p = 0.f;
#pragma unroll
    for (int i = 0; i < 8; ++i) {
      half2v x = __builtin_bit_cast(half2v, uu[i]);
      half2v z = x + xr2[i];
      half2v zl = __builtin_elementwise_max(z, z * negc);
      p = __builtin_amdgcn_fdot2(zl, at2[i], p, false);
    }
    m0 = p;
    float w = (e == 0) ? 1.f : 0.f;
    den = w;
#pragma unroll
    for (int i = 0; i < 8; ++i) {
      half2v x = __builtin_bit_cast(half2v, uu[i]);
      acc[2 * i] = w * (float)x[0];
      acc[2 * i + 1] = w * (float)x[1];
    }
  }

  int beg = rowptr[wid], end = rowptr[wid + 1];
  for (int base = beg; base < end; base += 8) {
    int idx = base + e;
    bool valid = idx < end;
    int ci = valid ? idx : end - 1;
    int s = csr[ci];
    const uint4* gp = reinterpret_cast<const uint4*>(xbase + (size_t)s * 256);
    uint4 u0 = gp[0], u1 = gp[1];
    unsigned uu[8] = {u0.x, u0.y, u0.z, u0.w, u1.x, u1.y, u1.z, u1.w};
    float p = 0.f;
#pragma unroll
    for (int i = 0; i < 8; ++i) {
      half2v x = __builtin_bit_cast(half2v, uu[i]);
      half2v z = x + xr2[i];
      half2v zl = __builtin_elementwise_max(z, z * negc);
      p = __builtin_amdgcn_fdot2(zl, at2[i], p, false);
    }
    float w = valid ? exp2f(p - m0) : 0.f;
    den += w;
#pragma unroll
    for (int i = 0; i < 8; ++i) {
      half2v x = __builtin_bit_cast(half2v, uu[i]);
      acc[2 * i] += w * (float)x[0];
      acc[2 * i + 1] += w * (float)x[1];
    }
  }

#pragma unroll
  for (int off = 1; off < 8; off <<= 1) {
    den += __shfl_xor(den, off, 64);
#pragma unroll
    for (int i = 0; i < 16; ++i) acc[i] += __shfl_xor(acc[i], off, 64);
  }

  float inv = 1.f / (den + 1e-16f);
  int c = h * 16 + 2 * e;
  float2 bv = reinterpret_cast<const float2*>(gbias + c)[0];
  float o0 = acc[2 * e] * inv + bv.x;
  float o1 = acc[2 * e + 1] * inv + bv.y;
  float s1 = o0 + o1;
  float s2 = o0 * o0 + o1 * o1;
#pragma unroll
  for (int off = 1; off < 64; off <<= 1) {
    s1 += __shfl_xor(s1, off, 64);
    s2 += __shfl_xor(s2, off, 64);
  }
  float mu = s1 * (1.f / 128.f);
  float var = s2 * (1.f / 128.f) - mu * mu;
  float rstd = rsqrtf(var + 1e-5f);
  float2 gvv = reinterpret_cast<const float2*>(lng + c)[0];
  float2 lbv = reinterpret_cast<const float2*>(lnb + c)[0];
  float e0 = (o0 - mu) * rstd * gvv.x + lbv.x;
  float e1 = (o1 - mu) * rstd * gvv.y + lbv.y;
  e0 = e0 > 0.f ? e0 : exp2f(e0 * LOG2E_) - 1.f;
  e1 = e1 > 0.f ? e1 : exp2f(e1 * LOG2E_) - 1.f;
  half2v o;
  o[0] = (_Float16)e0;
  o[1] = (_Float16)e1;
  reinterpret_cast<half2v*>(out)[wid * 64 + (c >> 1)] = o;
}

// ---------------- SAGE mean aggregation; fp16 in/out; lane = (group, edge-slot) (R11 body) ----------------
__global__ __launch_bounds__(256) void sage_agg_kernel(const _Float16* __restrict__ xp,
                                                       const int* __restrict__ rowptr,
                                                       const int* __restrict__ csr,
                                                       _Float16* __restrict__ mean, int n) {
  int wid = (blockIdx.x * 256 + threadIdx.x) >> 6;
  int lane = threadIdx.x & 63;
  if (wid >= n) return;
  const int g = lane >> 3, e = lane & 7;
  const char* __restrict__ xbase = (const char*)(xp + g * 16);

  float acc[16];
#pragma unroll
  for (int i = 0; i < 16; ++i) acc[i] = 0.f;

  int beg = rowptr[wid], end = rowptr[wid + 1];
  for (int base = beg; base < end; base += 8) {
    int idx = base + e;
    bool valid = idx < end;
    int ci = valid ? idx : end - 1;
    int s = csr[ci];
    const uint4* gp = reinterpret_cast<const uint4*>(xbase + (size_t)s * 256);
    uint4 u0 = gp[0], u1 = gp[1];
    unsigned uu[8] = {u0.x, u0.y, u0.z, u0.w, u1.x, u1.y, u1.z, u1.w};
    float w = valid ? 1.f : 0.f;
#pragma unroll
    for (int i = 0; i < 8; ++i) {
      half2v x = __builtin_bit_cast(half2v, uu[i]);
      acc[2 * i] += w * (float)x[0];
      acc[2 * i + 1] += w * (float)x[1];
    }
  }
#pragma unroll
  for (int off = 1; off < 8; off <<= 1) {
#pragma unroll
    for (int i = 0; i < 16; ++i) acc[i] += __shfl_xor(acc[i], off, 64);
  }
  float inv = 1.f / fmaxf((float)(end - beg), 1.f);
  int c = g * 16 + 2 * e;
  half2v o;
  o[0] = (_Float16)(acc[2 * e] * inv);
  o[1] = (_Float16)(acc[2 * e + 1] * inv);
  reinterpret_cast<half2v*>(mean)[wid * 64 + (c >> 1)] = o;
}

// ---------------- JK max + sigmoid gate + mean-pool (fp16 inputs) ----------------
__global__ __launch_bounds__(256) void jk_pool_kernel(const _Float16* __restrict__ x0,
                                                      const _Float16* __restrict__ x1,
                                                      const _Float16* __restrict__ x2,
                                                      const _Float16* __restrict__ x3,
                                                      const float* __restrict__ wap,
                                                      const float* __restrict__ bap,
                                                      const int* __restrict__ batch,
                                                      float* __restrict__ pooled,
                                                      float* __restrict__ cnt, int n,
                                                      int chunk) {
  int wid = (blockIdx.x * 256 + threadIdx.x) >> 6;
  int lane = threadIdx.x & 63;
  int start = wid * chunk;
  if (start >= n) return;
  int end = start + chunk;
  if (end > n) end = n;

  const float2 wv = reinterpret_cast<const float2*>(wap)[lane];
  const float b0 = bap[0];

  int cur = -1;
  float2 acc = make_float2(0.f, 0.f);
  float c = 0.f;

  for (int i = start; i < end; ++i) {
    int off = i * 64 + lane;
    half2v a0 = reinterpret_cast<const half2v*>(x0)[off];
    half2v a1 = reinterpret_cast<const half2v*>(x1)[off];
    half2v a2 = reinterpret_cast<const half2v*>(x2)[off];
    half2v a3 = reinterpret_cast<const half2v*>(x3)[off];
    half2v m01 = __builtin_elementwise_max(a0, a1);
    half2v m23 = __builtin_elementwise_max(a2, a3);
    half2v mm = __builtin_elementwise_max(m01, m23);
    float2 v = make_float2((float)mm[0], (float)mm[1]);
    float p = v.x * wv.x + v.y * wv.y;
#pragma unroll
    for (int o = 1; o < 64; o <<= 1) p += __shfl_xor(p, o, 64);
    float a = 1.f / (1.f + exp2f(-(p + b0) * LOG2E_));
    int bg = batch[i];
    if (bg != cur) {
      if (cur >= 0) {
        atomicAdd(&pooled[cur * 128 + 2 * lane], acc.x);
        atomicAdd(&pooled[cur * 128 + 2 * lane + 1], acc.y);
        if (lane == 0) atomicAdd(&cnt[cur], c);
      }
      cur = bg;
      acc = make_float2(0.f, 0.f);
      c = 0.f;
    }
    acc.x += v.x * a;
    acc.y += v.y * a;
    c += 1.f;
  }
  if (cur >= 0) {
    atomicAdd(&pooled[cur * 128 + 2 * lane], acc.x);
    atomicAdd(&pooled[cur * 128 + 2 * lane + 1], acc.y);
    if (lane == 0) atomicAdd(&cnt[cur], c);
  }
}

// ---------------- final MLP: one block per graph ----------------
__global__ __launch_bounds__(128) void mlp_kernel(const float* __restrict__ pooled,
                                                  const float* __restrict__ cnt,
                                                  const float* __restrict__ Wc1,
                                                  const float* __restrict__ bc1,
                                                  const float* __restrict__ a1,
                                                  const float* __restrict__ Wc2,
                                                  const float* __restrict__ bc2,
                                                  const float* __restrict__ a2,
                                                  const float* __restrict__ Wc3,
                                                  const float* __restrict__ bc3,
                                                  float* __restrict__ out) {
  __shared__ float sh[128];
  __shared__ float sh2[128];
  __shared__ float sh3[64];
  int g = blockIdx.x, t = threadIdx.x;
  float inv = 1.f / fmaxf(cnt[g], 1.f);
  sh[t] = pooled[g * 128 + t] * inv;
  __syncthreads();
  float z = bc1[t];
  for (int k = 0; k < 128; ++k) z += sh[k] * Wc1[k * 128 + t];
  float al = a1[0];
  z = z >= 0.f ? z : al * z;
  sh2[t] = z;
  __syncthreads();
  if (t < 64) {
    float z2 = bc2[t];
    for (int k = 0; k < 128; ++k) z2 += sh2[k] * Wc2[k * 64 + t];
    float a2v = a2[0];
    z2 = z2 >= 0.f ? z2 : a2v * z2;
    sh3[t] = z2;
  }
  __syncthreads();
  if (t < 2) {
    float o = bc3[t];
    for (int k = 0; k < 64; ++k) o += sh3[k] * Wc3[k * 2 + t];
    out[g * 2 + t] = o;
  }
}

// ================= host =================
extern "C" void kernel_launch(void* const* d_in, const int* in_sizes, int n_in,
                              void* d_out, int out_size, void* d_ws, size_t ws_size,
                              hipStream_t stream) {
  const float* x = (const float*)d_in[0];
  const int* ei = (const int*)d_in[1];
  const int* batch = (const int*)d_in[2];
  const float* W_in = (const float*)d_in[3];
  const float* b_in = (const float*)d_in[4];
  const float* W_res = (const float*)d_in[5];
  const float* b_res = (const float*)d_in[6];
  const float* g0_Wl = (const float*)d_in[7];
  const float* g0_bl = (const float*)d_in[8];
  const float* g0_Wr = (const float*)d_in[9];
  const float* g0_br = (const float*)d_in[10];
  const float* g0_att = (const float*)d_in[11];
  const float* g0_bias = (const float*)d_in[12];
  const float* g2_Wl = (const float*)d_in[13];
  const float* g2_bl = (const float*)d_in[14];
  const float* g2_Wr = (const float*)d_in[15];
  const float* g2_br = (const float*)d_in[16];
  const float* g2_att = (const float*)d_in[17];
  const float* g2_bias = (const float*)d_in[18];
  const float* s1_Wp = (const float*)d_in[19];
  const float* s1_bp = (const float*)d_in[20];
  const float* s1_Wl = (const float*)d_in[21];
  const float* s1_bl = (const float*)d_in[22];
  const float* s1_Wr = (const float*)d_in[23];
  const float* s3_Wp = (const float*)d_in[24];
  const float* s3_bp = (const float*)d_in[25];
  const float* s3_Wl = (const float*)d_in[26];
  const float* s3_bl = (const float*)d_in[27];
  const float* s3_Wr = (const float*)d_in[28];
  const float* ln_g = (const float*)d_in[29];
  const float* ln_b = (const float*)d_in[30];
  const float* Wap = (const float*)d_in[31];
  const float* bap = (const float*)d_in[32];
  const float* Wc1 = (const float*)d_in[33];
  const float* bc1 = (const float*)d_in[34];
  const float* a1 = (const float*)d_in[35];
  const float* Wc2 = (const float*)d_in[36];
  const float* bc2 = (const float*)d_in[37];
  const float* a2 = (const float*)d_in[38];
  const float* Wc3 = (const float*)d_in[39];
  const float* bc3 = (const float*)d_in[40];
  float* out = (float*)d_out;

  char* w = (char*)d_ws;
  auto alloc = [&](size_t bytes) -> void* {
    void* p = (void*)w;
    w += (bytes + 255) & ~(size_t)255;
    return p;
  };
  int* deg_cursor = (int*)alloc((size_t)N_ * 4);
  int* rowptr = (int*)alloc((size_t)(N_ + 1) * 4);
  int* bscan = (int*)alloc(256 * 4);
  int* csr = (int*)alloc((size_t)E_ * 4);
  float* bsumf = (float*)alloc((size_t)HID_ * 4);
  float* pooled = (float*)alloc((size_t)G_ * HID_ * 4);
  float* cntf = (float*)alloc((size_t)G_ * 4);
  _Float16* wsp = (_Float16*)alloc((size_t)(16384 + 10 * 32768) * 2);
  size_t bigh = (size_t)N_ * HID_ * 2;
  _Float16* T1 = (_Float16*)alloc(bigh);
  _Float16* T2 = (_Float16*)alloc(bigh);
  _Float16* H0 = (_Float16*)alloc(bigh);
  _Float16* H1 = (_Float16*)alloc(bigh);
  _Float16* B0 = (_Float16*)alloc(bigh);
  _Float16* B1 = (_Float16*)alloc(bigh);
  _Float16* B2 = (_Float16*)alloc(bigh);
  _Float16* B3 = (_Float16*)alloc(bigh);

  const _Float16* WsT_h = wsp;
  const _Float16* WsT_l = wsp + 8192;
  auto WTh = [&](int j) { return (const _Float16*)(wsp + 16384 + j * 32768); };
  auto WTl = [&](int j) { return (const _Float16*)(wsp + 16384 + j * 32768 + 16384); };
  // j: 0 g0_Wl, 1 g0_Wr, 2 s1_Wp, 3 s1_Wl, 4 s1_Wr, 5 g2_Wl, 6 g2_Wr, 7 s3_Wp, 8 s3_Wl, 9 s3_Wr

  const int EB = (E_ + 255) / 256;
  const int NB256 = (N_ + 255) / 256;
  const int WB = (N_ + 3) / 4;
  const int GB = (N_ + 63) / 64;

  // ---- CSR build ----
  hipMemsetAsync(deg_cursor, 0, (size_t)N_ * 4, stream);
  hist_kernel<<<EB, 256, 0, stream>>>(ei + E_, deg_cursor, E_);
  scan1_kernel<<<NB256, 256, 0, stream>>>(deg_cursor, rowptr, bscan, N_);
  scan2_kernel<<<1, 256, 0, stream>>>(bscan, NB256);
  scan3_kernel<<<NB256, 256, 0, stream>>>(rowptr, deg_cursor, bscan, N_, E_);
  fill_kernel<<<EB, 256, 0, stream>>>(ei, ei + E_, deg_cursor, csr, E_);

  // ---- weight prep (incl. bias sum) ----
  prep_w_kernel<<<(8192 + 10 * 16384 + 128 + 255) / 256, 256, 0, stream>>>(
      W_in, W_res, b_in, b_res, g0_Wl, g0_Wr, s1_Wp, s1_Wl, s1_Wr, g2_Wl, g2_Wr, s3_Wp,
      s3_Wl, s3_Wr, wsp, bsumf);

  // ---- input proj ----
  gemm_rw_in<<<GB, 256, 0, stream>>>(x, WsT_h, WsT_l, bsumf, T2, N_);

  // ---- GAT layer 0 ----
  gemm_rw16_dual_gat<<<GB, 256, 0, stream>>>(T2, WTh(0), WTl(0), WTh(1), WTl(1), g0_bl,
                                             g0_br, H0, H1, N_);
  gat_ln_kernel<<<WB, 256, 0, stream>>>(H0, H1, g0_att, g0_bias, rowptr, csr,
                                        ln_g + 0 * 128, ln_b + 0 * 128, B0, N_);

  // ---- SAGE layer 1 ----
  gemm_rw16<ACT_RELU, _Float16><<<GB, 256, 0, stream>>>(B0, WTh(2), WTl(2), s1_bp, H0, N_);
  sage_agg_kernel<<<WB, 256, 0, stream>>>(H0, rowptr, csr, T1, N_);
  gemm_rw16_dual_sage<<<GB, 256, 0, stream>>>(T1, WTh(3), WTl(3), B0, WTh(4), WTl(4), s1_bl,
                                              ln_g + 1 * 128, ln_b + 1 * 128, B1, N_);

  // ---- GAT layer 2 ----
  gemm_rw16_dual_gat<<<GB, 256, 0, stream>>>(B1, WTh(5), WTl(5), WTh(6), WTl(6), g2_bl,
                                             g2_br, H0, H1, N_);
  gat_ln_kernel<<<WB, 256, 0, stream>>>(H0, H1, g2_att, g2_bias, rowptr, csr,
                                        ln_g + 2 * 128, ln_b + 2 * 128, B2, N_);

  // ---- SAGE layer 3 ----
  gemm_rw16<ACT_RELU, _Float16><<<GB, 256, 0, stream>>>(B2, WTh(7), WTl(7), s3_bp, H0, N_);
  sage_agg_kernel<<<WB, 256, 0, stream>>>(H0, rowptr, csr, T1, N_);
  gemm_rw16_dual_sage<<<GB, 256, 0, stream>>>(T1, WTh(8), WTl(8), B2, WTh(9), WTl(9), s3_bl,
                                              ln_g + 3 * 128, ln_b + 3 * 128, B3, N_);

  // ---- JK max + gate + pool + MLP ----
  hipMemsetAsync(pooled, 0, (size_t)G_ * HID_ * 4 + (size_t)G_ * 4, stream);
  {
    const int chunk = 12;
    int nwaves = (N_ + chunk - 1) / chunk;
    int nblocks = (nwaves + 3) / 4;
    jk_pool_kernel<<<nblocks, 256, 0, stream>>>(B0, B1, B2, B3, Wap, bap, batch,
                                                pooled, cntf, N_, chunk);
  }
  mlp_kernel<<<G_, 128, 0, stream>>>(pooled, cntf, Wc1, bc1, a1, Wc2, bc2, a2, Wc3, bc3, out);
}

// Round 14
// 606.548 us; speedup vs baseline: 1.2310x; 1.0510x over previous
//
#include <hip/hip_runtime.h>
#include <math.h>

constexpr int N_ = 50000;
constexpr int E_ = 800000;
constexpr int IN_ = 64;
constexpr int HID_ = 128;
constexpr int G_ = 64;
constexpr float NEG_ = 0.2f;
constexpr float LOG2E_ = 1.44269504088896340736f;

#define ACT_NONE 0
#define ACT_RELU 1

typedef _Float16 half8 __attribute__((ext_vector_type(8)));
typedef _Float16 half2v __attribute__((ext_vector_type(2)));
typedef float floatx4 __attribute__((ext_vector_type(4)));

// ---------------- CSR build ----------------
__global__ __launch_bounds__(256) void hist_kernel(const int* __restrict__ dst,
                                                   int* __restrict__ deg, int e) {
  int i = blockIdx.x * 256 + threadIdx.x;
  if (i < e) atomicAdd(&deg[dst[i]], 1);
}

__global__ __launch_bounds__(256) void scan1_kernel(const int* __restrict__ deg,
                                                    int* __restrict__ excl,
                                                    int* __restrict__ bscan, int n) {
  __shared__ int sh[256];
  int t = threadIdx.x;
  int i = blockIdx.x * 256 + t;
  int v = (i < n) ? deg[i] : 0;
  sh[t] = v;
  __syncthreads();
  for (int off = 1; off < 256; off <<= 1) {
    int y = (t >= off) ? sh[t - off] : 0;
    __syncthreads();
    sh[t] += y;
    __syncthreads();
  }
  int incl = sh[t];
  if (i < n) excl[i] = incl - v;
  if (t == 255) bscan[blockIdx.x] = incl;
}

__global__ __launch_bounds__(256) void scan2_kernel(int* __restrict__ data, int nb) {
  __shared__ int sh[256];
  int t = threadIdx.x;
  int v = (t < nb) ? data[t] : 0;
  sh[t] = v;
  __syncthreads();
  for (int off = 1; off < 256; off <<= 1) {
    int y = (t >= off) ? sh[t - off] : 0;
    __syncthreads();
    sh[t] += y;
    __syncthreads();
  }
  if (t < nb) data[t] = sh[t] - v;  // exclusive
}

__global__ __launch_bounds__(256) void scan3_kernel(int* __restrict__ rowptr,
                                                    int* __restrict__ cursor,
                                                    const int* __restrict__ bscan,
                                                    int n, int e) {
  int i = blockIdx.x * 256 + threadIdx.x;
  if (i < n) {
    int v = rowptr[i] + bscan[blockIdx.x];
    rowptr[i] = v;
    cursor[i] = v;
  }
  if (i == n) rowptr[n] = e;
}

__global__ __launch_bounds__(256) void fill_kernel(const int* __restrict__ src,
                                                   const int* __restrict__ dst,
                                                   int* __restrict__ cursor,
                                                   int* __restrict__ csr, int e) {
  int i = blockIdx.x * 256 + threadIdx.x;
  if (i < e) {
    int d = dst[i];
    int p = atomicAdd(&cursor[d], 1);
    csr[p] = src[i];
  }
}

// ---------------- weight prep: transpose + fp16 hi/lo split (+ bias sum fused) ----------------
__global__ __launch_bounds__(256) void prep_w_kernel(
    const float* __restrict__ W_in, const float* __restrict__ W_res,
    const float* __restrict__ b_in, const float* __restrict__ b_res,
    const float* __restrict__ m0, const float* __restrict__ m1,
    const float* __restrict__ m2, const float* __restrict__ m3,
    const float* __restrict__ m4, const float* __restrict__ m5,
    const float* __restrict__ m6, const float* __restrict__ m7,
    const float* __restrict__ m8, const float* __restrict__ m9,
    _Float16* __restrict__ dst, float* __restrict__ bsum) {
  int idx = blockIdx.x * 256 + threadIdx.x;
  if (idx < 8192) {
    int n = idx >> 6, k = idx & 63;
    float v = W_in[k * 128 + n] + W_res[k * 128 + n];
    _Float16 h = (_Float16)v;
    dst[idx] = h;
    dst[8192 + idx] = (_Float16)(v - (float)h);
  } else if (idx < 8192 + 10 * 16384) {
    int r = idx - 8192;
    int j = r >> 14;
    int e = r & 16383;
    int n = e >> 7, k = e & 127;
    const float* S;
    switch (j) {
      case 0: S = m0; break; case 1: S = m1; break; case 2: S = m2; break;
      case 3: S = m3; break; case 4: S = m4; break; case 5: S = m5; break;
      case 6: S = m6; break; case 7: S = m7; break; case 8: S = m8; break;
      default: S = m9; break;
    }
    float v = S[k * 128 + n];
    _Float16 h = (_Float16)v;
    _Float16* base = dst + 16384 + j * 32768;
    base[e] = h;                       // e == n*128+k
    base[16384 + e] = (_Float16)(v - (float)h);
  } else if (idx < 8192 + 10 * 16384 + 128) {
    int k = idx - (8192 + 10 * 16384);
    bsum[k] = b_in[k] + b_res[k];
  }
}

// ---------------- fp16 hi/lo split of 8 floats (input-proj GEMM only) ----------------
__device__ inline void split8v(float4 a, float4 b, half8& h, half8& l) {
  float v0 = a.x, v1 = a.y, v2 = a.z, v3 = a.w;
  float v4 = b.x, v5 = b.y, v6 = b.z, v7 = b.w;
  _Float16 h0 = (_Float16)v0, h1 = (_Float16)v1, h2 = (_Float16)v2, h3 = (_Float16)v3;
  _Float16 h4 = (_Float16)v4, h5 = (_Float16)v5, h6 = (_Float16)v6, h7 = (_Float16)v7;
  h[0] = h0; h[1] = h1; h[2] = h2; h[3] = h3; h[4] = h4; h[5] = h5; h[6] = h6; h[7] = h7;
  l[0] = (_Float16)(v0 - (float)h0); l[1] = (_Float16)(v1 - (float)h1);
  l[2] = (_Float16)(v2 - (float)h2); l[3] = (_Float16)(v3 - (float)h3);
  l[4] = (_Float16)(v4 - (float)h4); l[5] = (_Float16)(v5 - (float)h5);
  l[6] = (_Float16)(v6 - (float)h6); l[7] = (_Float16)(v7 - (float)h7);
}

// ---- input-proj GEMM (fp32 A, hi/lo split): C16 = A[M,64]@W + bias; 128 rows/block ----
__global__ __launch_bounds__(256, 2) void gemm_rw_in(const float* __restrict__ A,
                                                     const _Float16* __restrict__ Wh,
                                                     const _Float16* __restrict__ Wl,
                                                     const float* __restrict__ bias,
                                                     _Float16* __restrict__ C, int M) {
  constexpr int K1 = 64, KK = 2;
  const int t = threadIdx.x;
  const int wave = t >> 6, lane = t & 63;
  const int quad = lane >> 4, l16 = lane & 15;
  const int nt0 = wave * 2;

  half8 wh[2][KK], wl[2][KK];
  float bb[2];
  int col[2];
#pragma unroll
  for (int i = 0; i < 2; ++i) {
    col[i] = (nt0 + i) * 16 + l16;
    bb[i] = bias[col[i]];
#pragma unroll
    for (int k = 0; k < KK; ++k) {
      size_t off = (size_t)col[i] * K1 + k * 32 + quad * 8;
      wh[i][k] = *reinterpret_cast<const half8*>(Wh + off);
      wl[i][k] = *reinterpret_cast<const half8*>(Wl + off);
    }
  }
  const int r0 = blockIdx.x * 128;
#pragma unroll 1
  for (int tt = 0; tt < 8; ++tt) {
    int tb = r0 + tt * 16;
    if (tb >= M) break;
    int arow = tb + l16;
    if (arow >= M) arow = M - 1;
    const float* ap = A + (size_t)arow * K1 + quad * 8;
    floatx4 acc[2];
    acc[0] = (floatx4){0.f, 0.f, 0.f, 0.f};
    acc[1] = (floatx4){0.f, 0.f, 0.f, 0.f};
#pragma unroll
    for (int k = 0; k < KK; ++k) {
      float4 a0 = *reinterpret_cast<const float4*>(ap + k * 32);
      float4 a1 = *reinterpret_cast<const float4*>(ap + k * 32 + 4);
      half8 ah, al;
      split8v(a0, a1, ah, al);
      acc[0] = __builtin_amdgcn_mfma_f32_16x16x32_f16(ah, wh[0][k], acc[0], 0, 0, 0);
      acc[0] = __builtin_amdgcn_mfma_f32_16x16x32_f16(ah, wl[0][k], acc[0], 0, 0, 0);
      acc[0] = __builtin_amdgcn_mfma_f32_16x16x32_f16(al, wh[0][k], acc[0], 0, 0, 0);
      acc[1] = __builtin_amdgcn_mfma_f32_16x16x32_f16(ah, wh[1][k], acc[1], 0, 0, 0);
      acc[1] = __builtin_amdgcn_mfma_f32_16x16x32_f16(ah, wl[1][k], acc[1], 0, 0, 0);
      acc[1] = __builtin_amdgcn_mfma_f32_16x16x32_f16(al, wh[1][k], acc[1], 0, 0, 0);
    }
#pragma unroll
    for (int i = 0; i < 2; ++i) {
#pragma unroll
      for (int reg = 0; reg < 4; ++reg) {
        int r = tb + quad * 4 + reg;
        if (r < M) C[(size_t)r * 128 + col[i]] = (_Float16)(acc[i][reg] + bb[i]);
      }
    }
  }
}

// ---- fp16-A GEMM: C = act(A16[M,128]@W + bias); no split, 2 MFMA/tile; 128 rows/block ----
template <int ACT, typename OutT>
__global__ __launch_bounds__(256, 2) void gemm_rw16(const _Float16* __restrict__ A,
                                                    const _Float16* __restrict__ Wh,
                                                    const _Float16* __restrict__ Wl,
                                                    const float* __restrict__ bias,
                                                    OutT* __restrict__ C, int M) {
  const int t = threadIdx.x;
  const int wave = t >> 6, lane = t & 63;
  const int quad = lane >> 4, l16 = lane & 15;
  const int nt0 = wave * 2;

  half8 wh[2][4], wl[2][4];
  float bb[2];
  int col[2];
#pragma unroll
  for (int i = 0; i < 2; ++i) {
    col[i] = (nt0 + i) * 16 + l16;
    bb[i] = bias[col[i]];
#pragma unroll
    for (int k = 0; k < 4; ++k) {
      size_t off = (size_t)col[i] * 128 + k * 32 + quad * 8;
      wh[i][k] = *reinterpret_cast<const half8*>(Wh + off);
      wl[i][k] = *reinterpret_cast<const half8*>(Wl + off);
    }
  }
  const int r0 = blockIdx.x * 128;
#pragma unroll 1
  for (int tt = 0; tt < 8; ++tt) {
    int tb = r0 + tt * 16;
    if (tb >= M) break;
    int arow = tb + l16;
    if (arow >= M) arow = M - 1;
    const _Float16* ap = A + (size_t)arow * 128 + quad * 8;
    half8 a[4];
#pragma unroll
    for (int k = 0; k < 4; ++k) a[k] = *reinterpret_cast<const half8*>(ap + k * 32);
    floatx4 acc[2];
    acc[0] = (floatx4){0.f, 0.f, 0.f, 0.f};
    acc[1] = (floatx4){0.f, 0.f, 0.f, 0.f};
#pragma unroll
    for (int k = 0; k < 4; ++k) {
      acc[0] = __builtin_amdgcn_mfma_f32_16x16x32_f16(a[k], wh[0][k], acc[0], 0, 0, 0);
      acc[0] = __builtin_amdgcn_mfma_f32_16x16x32_f16(a[k], wl[0][k], acc[0], 0, 0, 0);
      acc[1] = __builtin_amdgcn_mfma_f32_16x16x32_f16(a[k], wh[1][k], acc[1], 0, 0, 0);
      acc[1] = __builtin_amdgcn_mfma_f32_16x16x32_f16(a[k], wl[1][k], acc[1], 0, 0, 0);
    }
#pragma unroll
    for (int i = 0; i < 2; ++i) {
#pragma unroll
      for (int reg = 0; reg < 4; ++reg) {
        int r = tb + quad * 4 + reg;
        if (r < M) {
          float v = acc[i][reg] + bb[i];
          if (ACT == ACT_RELU) v = fmaxf(v, 0.f);
          C[(size_t)r * 128 + col[i]] = (OutT)v;
        }
      }
    }
  }
}

// ---- fp16-A dual-output GEMM (GAT): C0 = A@W0+b0, C1 = A@W1+b1; 128 rows/block ----
__global__ __launch_bounds__(256, 2) void gemm_rw16_dual_gat(const _Float16* __restrict__ A,
                                                             const _Float16* __restrict__ W0h,
                                                             const _Float16* __restrict__ W0l,
                                                             const _Float16* __restrict__ W1h,
                                                             const _Float16* __restrict__ W1l,
                                                             const float* __restrict__ b0,
                                                             const float* __restrict__ b1,
                                                             _Float16* __restrict__ C0,
                                                             _Float16* __restrict__ C1, int M) {
  const int t = threadIdx.x;
  const int wave = t >> 6, lane = t & 63;
  const int quad = lane >> 4, l16 = lane & 15;
  const int nt0 = wave * 2;

  half8 w0h[2][4], w0l[2][4], w1h[2][4], w1l[2][4];
  float bb0[2], bb1[2];
  int col[2];
#pragma unroll
  for (int i = 0; i < 2; ++i) {
    col[i] = (nt0 + i) * 16 + l16;
    bb0[i] = b0[col[i]];
    bb1[i] = b1[col[i]];
#pragma unroll
    for (int k = 0; k < 4; ++k) {
      size_t off = (size_t)col[i] * 128 + k * 32 + quad * 8;
      w0h[i][k] = *reinterpret_cast<const half8*>(W0h + off);
      w0l[i][k] = *reinterpret_cast<const half8*>(W0l + off);
      w1h[i][k] = *reinterpret_cast<const half8*>(W1h + off);
      w1l[i][k] = *reinterpret_cast<const half8*>(W1l + off);
    }
  }
  const int r0 = blockIdx.x * 128;
#pragma unroll 1
  for (int tt = 0; tt < 8; ++tt) {
    int tb = r0 + tt * 16;
    if (tb >= M) break;
    int arow = tb + l16;
    if (arow >= M) arow = M - 1;
    const _Float16* ap = A + (size_t)arow * 128 + quad * 8;
    half8 a[4];
#pragma unroll
    for (int k = 0; k < 4; ++k) a[k] = *reinterpret_cast<const half8*>(ap + k * 32);
    floatx4 acc0[2], acc1[2];
    acc0[0] = (floatx4){0.f, 0.f, 0.f, 0.f};
    acc0[1] = (floatx4){0.f, 0.f, 0.f, 0.f};
    acc1[0] = (floatx4){0.f, 0.f, 0.f, 0.f};
    acc1[1] = (floatx4){0.f, 0.f, 0.f, 0.f};
#pragma unroll
    for (int k = 0; k < 4; ++k) {
#pragma unroll
      for (int i = 0; i < 2; ++i) {
        acc0[i] = __builtin_amdgcn_mfma_f32_16x16x32_f16(a[k], w0h[i][k], acc0[i], 0, 0, 0);
        acc0[i] = __builtin_amdgcn_mfma_f32_16x16x32_f16(a[k], w0l[i][k], acc0[i], 0, 0, 0);
        acc1[i] = __builtin_amdgcn_mfma_f32_16x16x32_f16(a[k], w1h[i][k], acc1[i], 0, 0, 0);
        acc1[i] = __builtin_amdgcn_mfma_f32_16x16x32_f16(a[k], w1l[i][k], acc1[i], 0, 0, 0);
      }
    }
#pragma unroll
    for (int i = 0; i < 2; ++i) {
#pragma unroll
      for (int reg = 0; reg < 4; ++reg) {
        int r = tb + quad * 4 + reg;
        if (r < M) {
          C0[(size_t)r * 128 + col[i]] = (_Float16)(acc0[i][reg] + bb0[i]);
          C1[(size_t)r * 128 + col[i]] = (_Float16)(acc1[i][reg] + bb1[i]);
        }
      }
    }
  }
}

// ---- fp16-A dual-A GEMM (SAGE) + fused L2norm + LN + leaky; fp16 out; 128 rows/block ----
__global__ __launch_bounds__(256, 2) void gemm_rw16_dual_sage(const _Float16* __restrict__ A1,
                                                              const _Float16* __restrict__ W1h,
                                                              const _Float16* __restrict__ W1l,
                                                              const _Float16* __restrict__ A2,
                                                              const _Float16* __restrict__ W2h,
                                                              const _Float16* __restrict__ W2l,
                                                              const float* __restrict__ bias,
                                                              const float* __restrict__ lng,
                                                              const float* __restrict__ lnb,
                                                              _Float16* __restrict__ C, int M) {
  const int t = threadIdx.x;
  const int wave = t >> 6, lane = t & 63;
  const int quad = lane >> 4, l16 = lane & 15;
  const int nt0 = wave * 2;

  half8 w1h[2][4], w1l[2][4], w2h[2][4], w2l[2][4];
  float bb[2], gg[2], lb[2];
  int col[2];
#pragma unroll
  for (int i = 0; i < 2; ++i) {
    col[i] = (nt0 + i) * 16 + l16;
    bb[i] = bias[col[i]];
    gg[i] = lng[col[i]];
    lb[i] = lnb[col[i]];
#pragma unroll
    for (int k = 0; k < 4; ++k) {
      size_t off = (size_t)col[i] * 128 + k * 32 + quad * 8;
      w1h[i][k] = *reinterpret_cast<const half8*>(W1h + off);
      w1l[i][k] = *reinterpret_cast<const half8*>(W1l + off);
      w2h[i][k] = *reinterpret_cast<const half8*>(W2h + off);
      w2l[i][k] = *reinterpret_cast<const half8*>(W2l + off);
    }
  }
  __shared__ float2 red[2][4][16];  // [tile parity][wave][row]
  const int r0 = blockIdx.x * 128;
#pragma unroll 1
  for (int tt = 0; tt < 8; ++tt) {
    int tb = r0 + tt * 16;
    if (tb >= M) break;
    int arow = tb + l16;
    if (arow >= M) arow = M - 1;
    const _Float16* ap1 = A1 + (size_t)arow * 128 + quad * 8;
    const _Float16* ap2 = A2 + (size_t)arow * 128 + quad * 8;
    half8 a[4], b[4];
#pragma unroll
    for (int k = 0; k < 4; ++k) {
      a[k] = *reinterpret_cast<const half8*>(ap1 + k * 32);
      b[k] = *reinterpret_cast<const half8*>(ap2 + k * 32);
    }
    floatx4 acc[2];
    acc[0] = (floatx4){0.f, 0.f, 0.f, 0.f};
    acc[1] = (floatx4){0.f, 0.f, 0.f, 0.f};
#pragma unroll
    for (int k = 0; k < 4; ++k) {
#pragma unroll
      for (int i = 0; i < 2; ++i) {
        acc[i] = __builtin_amdgcn_mfma_f32_16x16x32_f16(a[k], w1h[i][k], acc[i], 0, 0, 0);
        acc[i] = __builtin_amdgcn_mfma_f32_16x16x32_f16(a[k], w1l[i][k], acc[i], 0, 0, 0);
        acc[i] = __builtin_amdgcn_mfma_f32_16x16x32_f16(b[k], w2h[i][k], acc[i], 0, 0, 0);
        acc[i] = __builtin_amdgcn_mfma_f32_16x16x32_f16(b[k], w2l[i][k], acc[i], 0, 0, 0);
      }
    }
    float v0[4], v1[4], p1[4], p2[4];
#pragma unroll
    for (int reg = 0; reg < 4; ++reg) {
      v0[reg] = acc[0][reg] + bb[0];
      v1[reg] = acc[1][reg] + bb[1];
      p1[reg] = v0[reg] + v1[reg];
      p2[reg] = v0[reg] * v0[reg] + v1[reg] * v1[reg];
    }
#pragma unroll
    for (int off = 1; off < 16; off <<= 1) {
#pragma unroll
      for (int reg = 0; reg < 4; ++reg) {
        p1[reg] += __shfl_xor(p1[reg], off, 64);
        p2[reg] += __shfl_xor(p2[reg], off, 64);
      }
    }
    int par = tt & 1;
    if (l16 == 0) {
#pragma unroll
      for (int reg = 0; reg < 4; ++reg)
        red[par][wave][quad * 4 + reg] = make_float2(p1[reg], p2[reg]);
    }
    __syncthreads();
#pragma unroll
    for (int reg = 0; reg < 4; ++reg) {
      int rr = quad * 4 + reg;
      float2 q0 = red[par][0][rr], q1 = red[par][1][rr];
      float2 q2 = red[par][2][rr], q3 = red[par][3][rr];
      float s1 = q0.x + q1.x + q2.x + q3.x;
      float s2 = q0.y + q1.y + q2.y + q3.y;
      float inv = 1.f / fmaxf(sqrtf(s2), 1e-12f);
      float mu = s1 * inv * (1.f / 128.f);
      float ex2 = (s2 * inv) * inv * (1.f / 128.f);
      float rstd = rsqrtf(ex2 - mu * mu + 1e-5f);
      int r = tb + rr;
      if (r < M) {
        float o0 = (v0[reg] * inv - mu) * rstd * gg[0] + lb[0];
        float o1 = (v1[reg] * inv - mu) * rstd * gg[1] + lb[1];
        o0 = fmaxf(o0, NEG_ * o0);
        o1 = fmaxf(o1, NEG_ * o1);
        C[(size_t)r * 128 + col[0]] = (_Float16)o0;
        C[(size_t)r * 128 + col[1]] = (_Float16)o1;
      }
    }
  }
}

// ---------------- GATv2 + LN + ELU; lane=(head, edge-slot); fp16 in/out (R13 body) ----------------
__global__ __launch_bounds__(256) void gat_ln_kernel(const _Float16* __restrict__ xl,
                                                     const _Float16* __restrict__ xr,
                                                     const float* __restrict__ att,
                                                     const float* __restrict__ gbias,
                                                     const int* __restrict__ rowptr,
                                                     const int* __restrict__ csr,
                                                     const float* __restrict__ lng,
                                                     const float* __restrict__ lnb,
                                                     _Float16* __restrict__ out, int n) {
  int wid = (blockIdx.x * 256 + threadIdx.x) >> 6;
  int lane = threadIdx.x & 63;
  if (wid >= n) return;
  const int h = lane >> 3, e = lane & 7;
  const char* __restrict__ xbase = (const char*)(xl + h * 16);

  half2v xr2[8], at2[8];
  {
    const uint4* xrp = reinterpret_cast<const uint4*>(xr + (size_t)wid * 128 + h * 16);
    uint4 u0 = xrp[0], u1 = xrp[1];
    unsigned uu[8] = {u0.x, u0.y, u0.z, u0.w, u1.x, u1.y, u1.z, u1.w};
#pragma unroll
    for (int i = 0; i < 8; ++i) xr2[i] = __builtin_bit_cast(half2v, uu[i]);
    const float2* ap = reinterpret_cast<const float2*>(att + h * 16);
#pragma unroll
    for (int i = 0; i < 8; ++i) {
      float2 a = ap[i];
      at2[i][0] = (_Float16)(a.x * LOG2E_);
      at2[i][1] = (_Float16)(a.y * LOG2E_);
    }
  }
  const half2v negc = {(_Float16)NEG_, (_Float16)NEG_};

  float m0, den;
  float acc[16];
  {
    const uint4* sp = reinterpret_cast<const uint4*>(xbase + (size_t)wid * 256);
    uint4 u0 = sp[0], u1 = sp[1];
    unsigned uu[8] = {u0.x, u0.y, u0.z, u0.w, u1.x, u1.y, u1.z, u1.w};
    float p = 0.f;
#pragma unroll
    for (int i = 0; i < 8; ++i) {
      half2v x = __builtin_bit_cast(half2v, uu[i]);
      half2v z = x + xr2[i];
      half2v zl = __builtin_elementwise_max(z, z * negc);
      p = __builtin_amdgcn_fdot2(zl, at2[i], p, false);
    }
    m0 = p;
    float w = (e == 0) ? 1.f : 0.f;
    den = w;
#pragma unroll
    for (int i = 0; i < 8; ++i) {
      half2v x = __builtin_bit_cast(half2v, uu[i]);
      acc[2 * i] = w * (float)x[0];
      acc[2 * i + 1] = w * (float)x[1];
    }
  }

  int beg = rowptr[wid], end = rowptr[wid + 1];
  for (int base = beg; base < end; base += 8) {
    int idx = base + e;
    bool valid = idx < end;
    int ci = valid ? idx : end - 1;
    int s = csr[ci];
    const uint4* gp = reinterpret_cast<const uint4*>(xbase + (size_t)s * 256);
    uint4 u0 = gp[0], u1 = gp[1];
    unsigned uu[8] = {u0.x, u0.y, u0.z, u0.w, u1.x, u1.y, u1.z, u1.w};
    float p = 0.f;
#pragma unroll
    for (int i = 0; i < 8; ++i) {
      half2v x = __builtin_bit_cast(half2v, uu[i]);
      half2v z = x + xr2[i];
      half2v zl = __builtin_elementwise_max(z, z * negc);
      p = __builtin_amdgcn_fdot2(zl, at2[i], p, false);
    }
    float w = valid ? exp2f(p - m0) : 0.f;
    den += w;
#pragma unroll
    for (int i = 0; i < 8; ++i) {
      half2v x = __builtin_bit_cast(half2v, uu[i]);
      acc[2 * i] += w * (float)x[0];
      acc[2 * i + 1] += w * (float)x[1];
    }
  }

#pragma unroll
  for (int off = 1; off < 8; off <<= 1) {
    den += __shfl_xor(den, off, 64);
#pragma unroll
    for (int i = 0; i < 16; ++i) acc[i] += __shfl_xor(acc[i], off, 64);
  }

  float inv = 1.f / (den + 1e-16f);
  int c = h * 16 + 2 * e;
  float2 bv = reinterpret_cast<const float2*>(gbias + c)[0];
  float o0 = acc[2 * e] * inv + bv.x;
  float o1 = acc[2 * e + 1] * inv + bv.y;
  float s1 = o0 + o1;
  float s2 = o0 * o0 + o1 * o1;
#pragma unroll
  for (int off = 1; off < 64; off <<= 1) {
    s1 += __shfl_xor(s1, off, 64);
    s2 += __shfl_xor(s2, off, 64);
  }
  float mu = s1 * (1.f / 128.f);
  float var = s2 * (1.f / 128.f) - mu * mu;
  float rstd = rsqrtf(var + 1e-5f);
  float2 gvv = reinterpret_cast<const float2*>(lng + c)[0];
  float2 lbv = reinterpret_cast<const float2*>(lnb + c)[0];
  float e0 = (o0 - mu) * rstd * gvv.x + lbv.x;
  float e1 = (o1 - mu) * rstd * gvv.y + lbv.y;
  e0 = e0 > 0.f ? e0 : exp2f(e0 * LOG2E_) - 1.f;
  e1 = e1 > 0.f ? e1 : exp2f(e1 * LOG2E_) - 1.f;
  half2v o;
  o[0] = (_Float16)e0;
  o[1] = (_Float16)e1;
  reinterpret_cast<half2v*>(out)[wid * 64 + (c >> 1)] = o;
}

// ---------------- SAGE mean aggregation; fp16 in/out; lane = (group, edge-slot) (R13 body) ----------------
__global__ __launch_bounds__(256) void sage_agg_kernel(const _Float16* __restrict__ xp,
                                                       const int* __restrict__ rowptr,
                                                       const int* __restrict__ csr,
                                                       _Float16* __restrict__ mean, int n) {
  int wid = (blockIdx.x * 256 + threadIdx.x) >> 6;
  int lane = threadIdx.x & 63;
  if (wid >= n) return;
  const int g = lane >> 3, e = lane & 7;
  const char* __restrict__ xbase = (const char*)(xp + g * 16);

  float acc[16];
#pragma unroll
  for (int i = 0; i < 16; ++i) acc[i] = 0.f;

  int beg = rowptr[wid], end = rowptr[wid + 1];
  for (int base = beg; base < end; base += 8) {
    int idx = base + e;
    bool valid = idx < end;
    int ci = valid ? idx : end - 1;
    int s = csr[ci];
    const uint4* gp = reinterpret_cast<const uint4*>(xbase + (size_t)s * 256);
    uint4 u0 = gp[0], u1 = gp[1];
    unsigned uu[8] = {u0.x, u0.y, u0.z, u0.w, u1.x, u1.y, u1.z, u1.w};
    float w = valid ? 1.f : 0.f;
#pragma unroll
    for (int i = 0; i < 8; ++i) {
      half2v x = __builtin_bit_cast(half2v, uu[i]);
      acc[2 * i] += w * (float)x[0];
      acc[2 * i + 1] += w * (float)x[1];
    }
  }
#pragma unroll
  for (int off = 1; off < 8; off <<= 1) {
#pragma unroll
    for (int i = 0; i < 16; ++i) acc[i] += __shfl_xor(acc[i], off, 64);
  }
  float inv = 1.f / fmaxf((float)(end - beg), 1.f);
  int c = g * 16 + 2 * e;
  half2v o;
  o[0] = (_Float16)(acc[2 * e] * inv);
  o[1] = (_Float16)(acc[2 * e + 1] * inv);
  reinterpret_cast<half2v*>(mean)[wid * 64 + (c >> 1)] = o;
}

// ---------------- JK max + sigmoid gate + mean-pool (fp16 inputs) ----------------
__global__ __launch_bounds__(256) void jk_pool_kernel(const _Float16* __restrict__ x0,
                                                      const _Float16* __restrict__ x1,
                                                      const _Float16* __restrict__ x2,
                                                      const _Float16* __restrict__ x3,
                                                      const float* __restrict__ wap,
                                                      const float* __restrict__ bap,
                                                      const int* __restrict__ batch,
                                                      float* __restrict__ pooled,
                                                      float* __restrict__ cnt, int n,
                                                      int chunk) {
  int wid = (blockIdx.x * 256 + threadIdx.x) >> 6;
  int lane = threadIdx.x & 63;
  int start = wid * chunk;
  if (start >= n) return;
  int end = start + chunk;
  if (end > n) end = n;

  const float2 wv = reinterpret_cast<const float2*>(wap)[lane];
  const float b0 = bap[0];

  int cur = -1;
  float2 acc = make_float2(0.f, 0.f);
  float c = 0.f;

  for (int i = start; i < end; ++i) {
    int off = i * 64 + lane;
    half2v a0 = reinterpret_cast<const half2v*>(x0)[off];
    half2v a1 = reinterpret_cast<const half2v*>(x1)[off];
    half2v a2 = reinterpret_cast<const half2v*>(x2)[off];
    half2v a3 = reinterpret_cast<const half2v*>(x3)[off];
    half2v m01 = __builtin_elementwise_max(a0, a1);
    half2v m23 = __builtin_elementwise_max(a2, a3);
    half2v mm = __builtin_elementwise_max(m01, m23);
    float2 v = make_float2((float)mm[0], (float)mm[1]);
    float p = v.x * wv.x + v.y * wv.y;
#pragma unroll
    for (int o = 1; o < 64; o <<= 1) p += __shfl_xor(p, o, 64);
    float a = 1.f / (1.f + exp2f(-(p + b0) * LOG2E_));
    int bg = batch[i];
    if (bg != cur) {
      if (cur >= 0) {
        atomicAdd(&pooled[cur * 128 + 2 * lane], acc.x);
        atomicAdd(&pooled[cur * 128 + 2 * lane + 1], acc.y);
        if (lane == 0) atomicAdd(&cnt[cur], c);
      }
      cur = bg;
      acc = make_float2(0.f, 0.f);
      c = 0.f;
    }
    acc.x += v.x * a;
    acc.y += v.y * a;
    c += 1.f;
  }
  if (cur >= 0) {
    atomicAdd(&pooled[cur * 128 + 2 * lane], acc.x);
    atomicAdd(&pooled[cur * 128 + 2 * lane + 1], acc.y);
    if (lane == 0) atomicAdd(&cnt[cur], c);
  }
}

// ---------------- final MLP: one block per graph ----------------
__global__ __launch_bounds__(128) void mlp_kernel(const float* __restrict__ pooled,
                                                  const float* __restrict__ cnt,
                                                  const float* __restrict__ Wc1,
                                                  const float* __restrict__ bc1,
                                                  const float* __restrict__ a1,
                                                  const float* __restrict__ Wc2,
                                                  const float* __restrict__ bc2,
                                                  const float* __restrict__ a2,
                                                  const float* __restrict__ Wc3,
                                                  const float* __restrict__ bc3,
                                                  float* __restrict__ out) {
  __shared__ float sh[128];
  __shared__ float sh2[128];
  __shared__ float sh3[64];
  int g = blockIdx.x, t = threadIdx.x;
  float inv = 1.f / fmaxf(cnt[g], 1.f);
  sh[t] = pooled[g * 128 + t] * inv;
  __syncthreads();
  float z = bc1[t];
  for (int k = 0; k < 128; ++k) z += sh[k] * Wc1[k * 128 + t];
  float al = a1[0];
  z = z >= 0.f ? z : al * z;
  sh2[t] = z;
  __syncthreads();
  if (t < 64) {
    float z2 = bc2[t];
    for (int k = 0; k < 128; ++k) z2 += sh2[k] * Wc2[k * 64 + t];
    float a2v = a2[0];
    z2 = z2 >= 0.f ? z2 : a2v * z2;
    sh3[t] = z2;
  }
  __syncthreads();
  if (t < 2) {
    float o = bc3[t];
    for (int k = 0; k < 64; ++k) o += sh3[k] * Wc3[k * 2 + t];
    out[g * 2 + t] = o;
  }
}

// ================= host =================
extern "C" void kernel_launch(void* const* d_in, const int* in_sizes, int n_in,
                              void* d_out, int out_size, void* d_ws, size_t ws_size,
                              hipStream_t stream) {
  const float* x = (const float*)d_in[0];
  const int* ei = (const int*)d_in[1];
  const int* batch = (const int*)d_in[2];
  const float* W_in = (const float*)d_in[3];
  const float* b_in = (const float*)d_in[4];
  const float* W_res = (const float*)d_in[5];
  const float* b_res = (const float*)d_in[6];
  const float* g0_Wl = (const float*)d_in[7];
  const float* g0_bl = (const float*)d_in[8];
  const float* g0_Wr = (const float*)d_in[9];
  const float* g0_br = (const float*)d_in[10];
  const float* g0_att = (const float*)d_in[11];
  const float* g0_bias = (const float*)d_in[12];
  const float* g2_Wl = (const float*)d_in[13];
  const float* g2_bl = (const float*)d_in[14];
  const float* g2_Wr = (const float*)d_in[15];
  const float* g2_br = (const float*)d_in[16];
  const float* g2_att = (const float*)d_in[17];
  const float* g2_bias = (const float*)d_in[18];
  const float* s1_Wp = (const float*)d_in[19];
  const float* s1_bp = (const float*)d_in[20];
  const float* s1_Wl = (const float*)d_in[21];
  const float* s1_bl = (const float*)d_in[22];
  const float* s1_Wr = (const float*)d_in[23];
  const float* s3_Wp = (const float*)d_in[24];
  const float* s3_bp = (const float*)d_in[25];
  const float* s3_Wl = (const float*)d_in[26];
  const float* s3_bl = (const float*)d_in[27];
  const float* s3_Wr = (const float*)d_in[28];
  const float* ln_g = (const float*)d_in[29];
  const float* ln_b = (const float*)d_in[30];
  const float* Wap = (const float*)d_in[31];
  const float* bap = (const float*)d_in[32];
  const float* Wc1 = (const float*)d_in[33];
  const float* bc1 = (const float*)d_in[34];
  const float* a1 = (const float*)d_in[35];
  const float* Wc2 = (const float*)d_in[36];
  const float* bc2 = (const float*)d_in[37];
  const float* a2 = (const float*)d_in[38];
  const float* Wc3 = (const float*)d_in[39];
  const float* bc3 = (const float*)d_in[40];
  float* out = (float*)d_out;

  char* w = (char*)d_ws;
  auto alloc = [&](size_t bytes) -> void* {
    void* p = (void*)w;
    w += (bytes + 255) & ~(size_t)255;
    return p;
  };
  int* deg_cursor = (int*)alloc((size_t)N_ * 4);
  int* rowptr = (int*)alloc((size_t)(N_ + 1) * 4);
  int* bscan = (int*)alloc(256 * 4);
  int* csr = (int*)alloc((size_t)E_ * 4);
  float* bsumf = (float*)alloc((size_t)HID_ * 4);
  float* pooled = (float*)alloc((size_t)G_ * HID_ * 4);
  float* cntf = (float*)alloc((size_t)G_ * 4);
  _Float16* wsp = (_Float16*)alloc((size_t)(16384 + 10 * 32768) * 2);
  size_t bigh = (size_t)N_ * HID_ * 2;
  _Float16* T1 = (_Float16*)alloc(bigh);
  _Float16* T2 = (_Float16*)alloc(bigh);
  _Float16* H0 = (_Float16*)alloc(bigh);
  _Float16* H1 = (_Float16*)alloc(bigh);
  _Float16* B0 = (_Float16*)alloc(bigh);
  _Float16* B1 = (_Float16*)alloc(bigh);
  _Float16* B2 = (_Float16*)alloc(bigh);
  _Float16* B3 = (_Float16*)alloc(bigh);

  const _Float16* WsT_h = wsp;
  const _Float16* WsT_l = wsp + 8192;
  auto WTh = [&](int j) { return (const _Float16*)(wsp + 16384 + j * 32768); };
  auto WTl = [&](int j) { return (const _Float16*)(wsp + 16384 + j * 32768 + 16384); };
  // j: 0 g0_Wl, 1 g0_Wr, 2 s1_Wp, 3 s1_Wl, 4 s1_Wr, 5 g2_Wl, 6 g2_Wr, 7 s3_Wp, 8 s3_Wl, 9 s3_Wr

  const int EB = (E_ + 255) / 256;
  const int NB256 = (N_ + 255) / 256;
  const int WB = (N_ + 3) / 4;
  const int GB = (N_ + 127) / 128;   // 128 rows/block: 391 blocks <= 512 concurrent

  // ---- CSR build ----
  hipMemsetAsync(deg_cursor, 0, (size_t)N_ * 4, stream);
  hist_kernel<<<EB, 256, 0, stream>>>(ei + E_, deg_cursor, E_);
  scan1_kernel<<<NB256, 256, 0, stream>>>(deg_cursor, rowptr, bscan, N_);
  scan2_kernel<<<1, 256, 0, stream>>>(bscan, NB256);
  scan3_kernel<<<NB256, 256, 0, stream>>>(rowptr, deg_cursor, bscan, N_, E_);
  fill_kernel<<<EB, 256, 0, stream>>>(ei, ei + E_, deg_cursor, csr, E_);

  // ---- weight prep (incl. bias sum) ----
  prep_w_kernel<<<(8192 + 10 * 16384 + 128 + 255) / 256, 256, 0, stream>>>(
      W_in, W_res, b_in, b_res, g0_Wl, g0_Wr, s1_Wp, s1_Wl, s1_Wr, g2_Wl, g2_Wr, s3_Wp,
      s3_Wl, s3_Wr, wsp, bsumf);

  // ---- input proj ----
  gemm_rw_in<<<GB, 256, 0, stream>>>(x, WsT_h, WsT_l, bsumf, T2, N_);

  // ---- GAT layer 0 ----
  gemm_rw16_dual_gat<<<GB, 256, 0, stream>>>(T2, WTh(0), WTl(0), WTh(1), WTl(1), g0_bl,
                                             g0_br, H0, H1, N_);
  gat_ln_kernel<<<WB, 256, 0, stream>>>(H0, H1, g0_att, g0_bias, rowptr, csr,
                                        ln_g + 0 * 128, ln_b + 0 * 128, B0, N_);

  // ---- SAGE layer 1 ----
  gemm_rw16<ACT_RELU, _Float16><<<GB, 256, 0, stream>>>(B0, WTh(2), WTl(2), s1_bp, H0, N_);
  sage_agg_kernel<<<WB, 256, 0, stream>>>(H0, rowptr, csr, T1, N_);
  gemm_rw16_dual_sage<<<GB, 256, 0, stream>>>(T1, WTh(3), WTl(3), B0, WTh(4), WTl(4), s1_bl,
                                              ln_g + 1 * 128, ln_b + 1 * 128, B1, N_);

  // ---- GAT layer 2 ----
  gemm_rw16_dual_gat<<<GB, 256, 0, stream>>>(B1, WTh(5), WTl(5), WTh(6), WTl(6), g2_bl,
                                             g2_br, H0, H1, N_);
  gat_ln_kernel<<<WB, 256, 0, stream>>>(H0, H1, g2_att, g2_bias, rowptr, csr,
                                        ln_g + 2 * 128, ln_b + 2 * 128, B2, N_);

  // ---- SAGE layer 3 ----
  gemm_rw16<ACT_RELU, _Float16><<<GB, 256, 0, stream>>>(B2, WTh(7), WTl(7), s3_bp, H0, N_);
  sage_agg_kernel<<<WB, 256, 0, stream>>>(H0, rowptr, csr, T1, N_);
  gemm_rw16_dual_sage<<<GB, 256, 0, stream>>>(T1, WTh(8), WTl(8), B2, WTh(9), WTl(9), s3_bl,
                                              ln_g + 3 * 128, ln_b + 3 * 128, B3, N_);

  // ---- JK max + gate + pool + MLP ----
  hipMemsetAsync(pooled, 0, (size_t)G_ * HID_ * 4 + (size_t)G_ * 4, stream);
  {
    const int chunk = 12;
    int nwaves = (N_ + chunk - 1) / chunk;
    int nblocks = (nwaves + 3) / 4;
    jk_pool_kernel<<<nblocks, 256, 0, stream>>>(B0, B1, B2, B3, Wap, bap, batch,
                                                pooled, cntf, N_, chunk);
  }
  mlp_kernel<<<G_, 128, 0, stream>>>(pooled, cntf, Wc1, bc1, a1, Wc2, bc2, a2, Wc3, bc3, out);
}